// Round 9
// baseline (170.445 us; speedup 1.0000x reference)
//
#include <hip/hip_runtime.h>
#include <hip/hip_bf16.h>
#include <cmath>

#define DIM 128
#define HEADS 8
#define NBATCH 2
#define NQ 6400   /* 80*80 */
#define NKV 1600  /* 40*40 */
#define NC 50     /* kv chunks of 32 */
#define BN_EPS 1e-5f
#define LOG2E 1.4426950408889634f

typedef __bf16 bf16_t;
typedef __attribute__((ext_vector_type(8))) __bf16 bf16x8;
typedef __attribute__((ext_vector_type(16))) float f32x16;

union BF8U { bf16x8 v; unsigned u[4]; };

// pack two f32 -> packed bf16 (a->lo, b->hi); lowers to v_cvt_pk_bf16_f32 (RNE)
__device__ inline unsigned packbf2(float a, float b) {
  union { __hip_bfloat162 v; unsigned u; } r;
  r.v = __float22bfloat162_rn(make_float2(a, b));
  return r.u;
}

__device__ inline unsigned short f2bf(float v) {
  unsigned u = __float_as_uint(v);
  return (unsigned short)((u + 0x7FFFu + ((u >> 16) & 1u)) >> 16);
}

// build bf16x8 B-fragment from 8 consecutive f32 weights (in-register cast)
__device__ inline bf16x8 ldw8(const float* __restrict__ p) {
  float4 w0 = *(const float4*)p;
  float4 w1 = *(const float4*)(p + 4);
  BF8U r;
  r.u[0] = packbf2(w0.x, w0.y);
  r.u[1] = packbf2(w0.z, w0.w);
  r.u[2] = packbf2(w1.x, w1.y);
  r.u[3] = packbf2(w1.z, w1.w);
  return r.v;
}

// ---------------------------------------------------------------------------
// Fused q + sr GEMM, reading from x with NO global staging buffers.
// blocks [0,200):   q tile. A (32 s x 128 c) staged f32->bf16 through LDS
//                   (coalesced float4 reads, b128 fragment reads), B = q_w
//                   cast in-register. -> Qb bf16 token-major, *SCALE*log2e.
// blocks [200,250): sr tile. A[m][c4] im2col gathered as float2 (kx pairs are
//                   adjacent in x; offsets unroll-time consts). BN+ReLU
//                   -> xkvb bf16 token-major.
// C/D: col o = lane&31, row s = (r&3)+8*(r>>2)+4*hf.
// ---------------------------------------------------------------------------
__global__ __launch_bounds__(256) void mgemm_qsr(
    const float* __restrict__ x,
    const float* __restrict__ q_w, const float* __restrict__ q_b,
    const float* __restrict__ sr_w, const float* __restrict__ sr_b,
    const float* __restrict__ bng, const float* __restrict__ bnb,
    const float* __restrict__ bnm, const float* __restrict__ bnv,
    unsigned short* __restrict__ Qb, unsigned short* __restrict__ xkvb,
    float sl)
{
  __shared__ __align__(16) unsigned short As[32][136];
  int t = threadIdx.x;
  int ln = t & 31, hf = (t >> 5) & 1, wid = t >> 6;
  int b = blockIdx.y;
  int o = wid * 32 + ln;
  f32x16 acc = {};

  if (blockIdx.x < 200) {            // ---- q part (C = 128) ----
    int s0 = blockIdx.x * 32;
    // stage A-tile: 1024 float4 (8 per c-row x 128 c), 4 per thread
    const float* xb = x + (size_t)b * DIM * NQ + s0;
#pragma unroll
    for (int it = 0; it < 4; ++it) {
      int idx = t + it * 256;
      int c = idx >> 3, s4 = (idx & 7) * 4;
      float4 v = *(const float4*)&xb[(size_t)c * NQ + s4];
      As[s4 + 0][c] = f2bf(v.x);
      As[s4 + 1][c] = f2bf(v.y);
      As[s4 + 2][c] = f2bf(v.z);
      As[s4 + 3][c] = f2bf(v.w);
    }
    __syncthreads();

    const float* brow = q_w + (size_t)o * 128 + hf * 8;
    const unsigned short* arow = &As[ln][hf * 8];
#pragma unroll
    for (int c0 = 0; c0 < 128; c0 += 16) {
      bf16x8 af = *(const bf16x8*)&arow[c0];
      acc = __builtin_amdgcn_mfma_f32_32x32x16_bf16(af, ldw8(&brow[c0]), acc, 0, 0, 0);
    }
    float bv = q_b[o];
#pragma unroll
    for (int g = 0; g < 4; ++g)
#pragma unroll
      for (int j = 0; j < 4; ++j) {
        int s = s0 + 8 * g + 4 * hf + j;
        Qb[((size_t)b * NQ + s) * DIM + o] = f2bf((acc[4 * g + j] + bv) * sl);
      }
  } else {                           // ---- sr part (C = 512, im2col) ----
    int s0 = (blockIdx.x - 200) * 32;
    int m = s0 + ln;
    int i = m / 40, jp = m % 40;
    const float* ab = x + (size_t)b * DIM * NQ + i * 160 + 2 * jp; // +c*6400+ky*80+kx
    const float* brow = sr_w + (size_t)o * 512 + hf * 8;
#pragma unroll 4
    for (int c0 = 0; c0 < 512; c0 += 16) {
      BF8U af;
#pragma unroll
      for (int jj = 0; jj < 4; ++jj) {
        int ca = c0 + hf * 8 + 2 * jj;              // kx=0; ca+1 is kx=1
        float2 v = *(const float2*)&ab[(size_t)(ca >> 2) * NQ + ((ca >> 1) & 1) * 80];
        af.u[jj] = packbf2(v.x, v.y);
      }
      acc = __builtin_amdgcn_mfma_f32_32x32x16_bf16(af.v, ldw8(&brow[c0]), acc, 0, 0, 0);
    }
    float bv = sr_b[o];
    float inv = bng[o] / sqrtf(bnv[o] + BN_EPS);
    float b2 = bnb[o] - bnm[o] * inv;
#pragma unroll
    for (int g = 0; g < 4; ++g)
#pragma unroll
      for (int j = 0; j < 4; ++j) {
        int s = s0 + 8 * g + 4 * hf + j;
        float v = fmaxf((acc[4 * g + j] + bv) * inv + b2, 0.f);
        xkvb[((size_t)b * NKV + s) * DIM + o] = f2bf(v);
      }
  }
}

// ---------------------------------------------------------------------------
// Fused k + v GEMM over xkvb (C=128). blockIdx.z: 0 = k, 1 = v.
// Weights cast in-register. Fragment-major epilogues (attention-coalesced):
// k -> Kp[(b*8+h)*50+chunk][s_local*16+d]
// v -> Vp[(b*8+h)*50+chunk][va:512 | vb:512] (kv-permuted identity w/ S-layout)
// v-branch also fills the softmax-denominator slots (lane16 rows = 1.0).
// ---------------------------------------------------------------------------
__global__ __launch_bounds__(256) void mgemm_kv(
    const bf16_t* __restrict__ xkvb,
    const float* __restrict__ k_w, const float* __restrict__ k_b,
    const float* __restrict__ v_w, const float* __restrict__ v_b,
    unsigned short* __restrict__ Kp, unsigned short* __restrict__ Vp)
{
  int t = threadIdx.x;
  int ln = t & 31, hf = (t >> 5) & 1, wid = t >> 6;
  int b = blockIdx.y;
  int isv = blockIdx.z;
  int s0 = blockIdx.x * 32;
  const float* W = isv ? v_w : k_w;
  int o = wid * 32 + ln;

  const bf16_t* arow = &xkvb[((size_t)b * NKV + s0 + ln) * DIM + hf * 8];
  const float* brow = W + (size_t)o * DIM + hf * 8;
  f32x16 acc = {};
#pragma unroll
  for (int c0 = 0; c0 < 128; c0 += 16) {
    bf16x8 af = *(const bf16x8*)&arow[c0];
    acc = __builtin_amdgcn_mfma_f32_32x32x16_bf16(af, ldw8(&brow[c0]), acc, 0, 0, 0);
  }

  int hloc = o >> 4, d = o & 15;
  if (isv) {
    float bv = v_b[o];
    size_t CB = (((size_t)b * HEADS + hloc) * NC + (s0 >> 5)) * 1024;
    uint4 w0, w1;
    w0.x = packbf2(acc[0] + bv, acc[1] + bv);
    w0.y = packbf2(acc[2] + bv, acc[3] + bv);
    w0.z = packbf2(acc[4] + bv, acc[5] + bv);
    w0.w = packbf2(acc[6] + bv, acc[7] + bv);
    w1.x = packbf2(acc[8] + bv, acc[9] + bv);
    w1.y = packbf2(acc[10] + bv, acc[11] + bv);
    w1.z = packbf2(acc[12] + bv, acc[13] + bv);
    w1.w = packbf2(acc[14] + bv, acc[15] + bv);
    *(uint4*)&Vp[CB + d * 16 + hf * 8] = w0;         // va block
    *(uint4*)&Vp[CB + 512 + d * 16 + hf * 8] = w1;   // vb block
    // denominator fill: lane-16 rows of both blocks = 1.0 bf16
    {
      int h2 = t >> 5, pos = t & 31;                 // 256 threads = 8h x 32pos
      size_t CB2 = (((size_t)b * HEADS + h2) * NC + (s0 >> 5)) * 1024;
      Vp[CB2 + 256 + ((pos & 16) ? 512 : 0) + (pos & 15)] = 0x3F80;
    }
  } else {
    float bv = k_b[o];
    size_t CB = (((size_t)b * HEADS + hloc) * NC + (s0 >> 5)) * 512;
#pragma unroll
    for (int g = 0; g < 4; ++g)
#pragma unroll
      for (int j = 0; j < 4; ++j) {
        int sl2 = 8 * g + 4 * hf + j;                // s_local row
        Kp[CB + sl2 * 16 + d] = f2bf(acc[4 * g + j] + bv);
      }
  }
}

// ---------------------------------------------------------------------------
// MFMA attention, kv-split = nsplit, fragment-major K/V, full register
// prefetch (round-7-measured 48 VGPR fits the 64-VGPR/8-waves-EU budget).
// nsplit=4 -> 12800 waves (12.5/SIMD). grid (50, 8, 2*nsplit), block 256.
// ---------------------------------------------------------------------------
__global__ __launch_bounds__(256, 8) void attn_split(
    const bf16_t* __restrict__ Qb, const bf16_t* __restrict__ Kp,
    const bf16_t* __restrict__ Vp, unsigned short* __restrict__ Pb,
    float* __restrict__ Lsum, int nsplit)
{
  const int t = threadIdx.x;
  const int ln = t & 31, hf = (t >> 5) & 1, wid = t >> 6;
  const int h = blockIdx.y;
  const int b = blockIdx.z & 1, quarter = blockIdx.z >> 1;
  const int q0 = blockIdx.x * 128 + wid * 32;
  const int base = NC / nsplit, rem = NC % nsplit;
  const int kcnt = base + (quarter < rem ? 1 : 0);
  const int kstart = quarter * base + (quarter < rem ? quarter : rem);
  const int slice = quarter * 2 + b;

  bf16x8 qf = *(const bf16x8*)&Qb[((size_t)b * NQ + q0 + ln) * DIM + h * 16 + hf * 8];
  const int bh = b * HEADS + h;
  const bf16_t* kc = &Kp[((size_t)bh * NC + kstart) * 512 + ln * 16 + hf * 8];
  const bf16_t* vc = &Vp[((size_t)bh * NC + kstart) * 1024 + ln * 16 + hf * 8];

  f32x16 acc = {};
  const f32x16 zero = {};

  bf16x8 kf = *(const bf16x8*)kc;
  bf16x8 va = *(const bf16x8*)vc;
  bf16x8 vb = *(const bf16x8*)(vc + 512);

  for (int c = 0; c < kcnt; ++c) {
    int cn = (c + 1 < kcnt) ? c + 1 : c;   // prefetch (last re-reads, discarded)
    bf16x8 kf2 = *(const bf16x8*)(kc + cn * 512);
    bf16x8 va2 = *(const bf16x8*)(vc + cn * 1024);
    bf16x8 vb2 = *(const bf16x8*)(vc + cn * 1024 + 512);

    f32x16 S = __builtin_amdgcn_mfma_f32_32x32x16_bf16(kf, qf, zero, 0, 0, 0);

    BF8U f0, f1;
#pragma unroll
    for (int i = 0; i < 4; ++i) {
      f0.u[i] = packbf2(__builtin_amdgcn_exp2f(S[2 * i]),
                        __builtin_amdgcn_exp2f(S[2 * i + 1]));
      f1.u[i] = packbf2(__builtin_amdgcn_exp2f(S[8 + 2 * i]),
                        __builtin_amdgcn_exp2f(S[9 + 2 * i]));
    }

    acc = __builtin_amdgcn_mfma_f32_32x32x16_bf16(va, f0.v, acc, 0, 0, 0);
    acc = __builtin_amdgcn_mfma_f32_32x32x16_bf16(vb, f1.v, acc, 0, 0, 0);
    kf = kf2; va = va2; vb = vb2;
  }

  // acc: col q = ln, row d = (r&3)+8*(r>>2)+4*hf. Row16 (denom) = acc[8]@hf0.
  unsigned short* prow =
      &Pb[(size_t)slice * (NQ * DIM) + (size_t)(q0 + ln) * DIM + h * 16 + 4 * hf];
  uint2 w0, w1;
  w0.x = packbf2(acc[0], acc[1]); w0.y = packbf2(acc[2], acc[3]);
  w1.x = packbf2(acc[4], acc[5]); w1.y = packbf2(acc[6], acc[7]);
  *(uint2*)&prow[0] = w0;
  *(uint2*)&prow[8] = w1;
  if (!hf)
    Lsum[(size_t)slice * (HEADS * NQ) + (size_t)h * NQ + q0 + ln] = acc[8];
}

// ---------------------------------------------------------------------------
// proj_comb: fused combine (nsplit partials) + reference scramble + proj GEMM.
// As[s_local][c] = sum_q(Pq)/sum_q(Lq) at flat att index f = c*6400+(s0+sl)
// (the transpose/reshape scramble). Coalesced Pb reads; weights cast in-reg.
// grid (200, 2), block 256.
// ---------------------------------------------------------------------------
__global__ __launch_bounds__(256) void proj_comb(
    const unsigned short* __restrict__ Pb, const float* __restrict__ Lsum,
    const float* __restrict__ p_w, const float* __restrict__ p_b,
    float* __restrict__ Out, int nsplit)
{
  __shared__ __align__(16) unsigned short As[32][136];
  int t = threadIdx.x;
  int b = blockIdx.y;
  int s0 = blockIdx.x * 32;

  {
    int tx = t & 31, cg = t >> 5;          // lane sweeps s (coalesced in f)
#pragma unroll
    for (int it = 0; it < 16; ++it) {
      int c = cg * 16 + it;
      int f = c * NQ + s0 + tx;            // flat att index = n*128 + h*16+d
      int n = f >> 7, hh = (f >> 4) & 7;
      float ps = 0.f, L = 0.f;
      for (int qq = 0; qq < nsplit; ++qq) {
        int sl2 = qq * 2 + b;
        ps += __uint_as_float((unsigned)Pb[(size_t)sl2 * (NQ * DIM) + f] << 16);
        L += Lsum[(size_t)sl2 * (HEADS * NQ) + (size_t)hh * NQ + n];
      }
      As[tx][c] = f2bf(ps / L);
    }
  }
  __syncthreads();

  int ln = t & 31, hf = (t >> 5) & 1, wid = t >> 6;
  int o = wid * 32 + ln;
  const float* brow = p_w + (size_t)o * DIM + hf * 8;
  const unsigned short* arow = &As[ln][hf * 8];
  f32x16 acc = {};
#pragma unroll
  for (int c0 = 0; c0 < 128; c0 += 16) {
    bf16x8 af = *(const bf16x8*)&arow[c0];
    acc = __builtin_amdgcn_mfma_f32_32x32x16_bf16(af, ldw8(&brow[c0]), acc, 0, 0, 0);
  }
  float bv = p_b[o];
  float* obase = &Out[((size_t)b * DIM + o) * NQ + s0 + 4 * hf];
#pragma unroll
  for (int g = 0; g < 4; ++g) {
    float4 r;
    r.x = acc[4 * g + 0] + bv; r.y = acc[4 * g + 1] + bv;
    r.z = acc[4 * g + 2] + bv; r.w = acc[4 * g + 3] + bv;
    *(float4*)&obase[8 * g] = r;
  }
}

// ---------------------------------------------------------------------------
extern "C" void kernel_launch(void* const* d_in, const int* in_sizes, int n_in,
                              void* d_out, int out_size, void* d_ws, size_t ws_size,
                              hipStream_t stream)
{
  const float* x    = (const float*)d_in[0];
  const float* q_w  = (const float*)d_in[1];
  const float* q_b  = (const float*)d_in[2];
  const float* k_w  = (const float*)d_in[3];
  const float* k_b  = (const float*)d_in[4];
  const float* v_w  = (const float*)d_in[5];
  const float* v_b  = (const float*)d_in[6];
  const float* sr_w = (const float*)d_in[7];
  const float* sr_b = (const float*)d_in[8];
  const float* bng  = (const float*)d_in[9];
  const float* bnb  = (const float*)d_in[10];
  const float* bnm  = (const float*)d_in[11];
  const float* bnv  = (const float*)d_in[12];
  const float* p_w  = (const float*)d_in[13];
  const float* p_b  = (const float*)d_in[14];
  float* out = (float*)d_out;

  // kv-split: 4 if workspace allows (20.48 MB), else 2. ws_size constant per
  // session -> identical behavior every call (graph-safe).
  const int nsplit = (ws_size >= (size_t)5120000 * 4) ? 4 : 2;

  float* ws = (float*)d_ws;
  // f32-slot layout (bf16 buffers use 2 elems/slot):
  //   Pb [0, nsplit*819200) -- attn partials (2*nsplit slices of NQ*128 bf16)
  //      xkvb nested at [0, 204800): dead before attn writes Pb.
  bf16_t* Pb   = (bf16_t*)ws;
  bf16_t* xkvb = (bf16_t*)ws;
  size_t off = (size_t)nsplit * 819200;
  bf16_t* Qb = (bf16_t*)(ws + off);   off += 819200;
  bf16_t* Kp = (bf16_t*)(ws + off);   off += 204800;
  bf16_t* Vp = (bf16_t*)(ws + off);   off += 409600;
  float* Lsum = ws + off;             // 2*nsplit*HEADS*NQ f32

  const float sl = 0.25f * LOG2E;  // SCALE * log2(e) folded into Q

  // 1. q (blocks 0-199, LDS-staged A) + sr conv/BN/ReLU (blocks 200-249)
  mgemm_qsr<<<dim3(250, NBATCH), dim3(256), 0, stream>>>(
      x, q_w, q_b, sr_w, sr_b, bng, bnb, bnm, bnv,
      (unsigned short*)Qb, (unsigned short*)xkvb, sl);

  // 2. k (z=0) + v (z=1), fragment-major epilogues + denom fill
  mgemm_kv<<<dim3(NKV / 32, NBATCH, 2), dim3(256), 0, stream>>>(
      xkvb, k_w, k_b, v_w, v_b, (unsigned short*)Kp, (unsigned short*)Vp);

  // 3. attention partials (kv-split = nsplit), prefetch + 8 waves/EU
  attn_split<<<dim3(NQ / 128, HEADS, 2 * nsplit), dim3(256), 0, stream>>>(
      Qb, Kp, Vp, (unsigned short*)Pb, Lsum, nsplit);

  // 4. combine + scramble + proj -> f32 chan-major final output (B,128,80,80)
  proj_comb<<<dim3(200, NBATCH), dim3(256), 0, stream>>>(
      (const unsigned short*)Pb, Lsum, p_w, p_b, out, nsplit);
}

// Round 10
// 166.764 us; speedup vs baseline: 1.0221x; 1.0221x over previous
//
#include <hip/hip_runtime.h>
#include <hip/hip_bf16.h>
#include <cmath>

#define DIM 128
#define HEADS 8
#define NBATCH 2
#define NQ 6400   /* 80*80 */
#define NKV 1600  /* 40*40 */
#define NC 50     /* kv chunks of 32 */
#define BN_EPS 1e-5f
#define LOG2E 1.4426950408889634f

typedef __bf16 bf16_t;
typedef __attribute__((ext_vector_type(8))) __bf16 bf16x8;
typedef __attribute__((ext_vector_type(16))) float f32x16;

union BF8U { bf16x8 v; unsigned u[4]; };

// pack two f32 -> packed bf16 (a->lo, b->hi); lowers to v_cvt_pk_bf16_f32 (RNE)
__device__ inline unsigned packbf2(float a, float b) {
  union { __hip_bfloat162 v; unsigned u; } r;
  r.v = __float22bfloat162_rn(make_float2(a, b));
  return r.u;
}

__device__ inline unsigned short f2bf(float v) {
  unsigned u = __float_as_uint(v);
  return (unsigned short)((u + 0x7FFFu + ((u >> 16) & 1u)) >> 16);
}

// ---------------------------------------------------------------------------
// prep_all (round-7 verbatim): fused transpose + im2col + weight cast + Vp
// denominator fill.
// blocks [0,1600):  x (B,128,6400) f32 -> Xb (B,6400,128) bf16 (LDS tile)
// blocks [1600,8000): e-indexed: im2col X4b[b][m][c4] + Wb cast + Vp lane-16
// ---------------------------------------------------------------------------
__global__ __launch_bounds__(256) void prep_all(
    const float* __restrict__ x,
    const float* __restrict__ qw, const float* __restrict__ kw,
    const float* __restrict__ vw, const float* __restrict__ pw,
    const float* __restrict__ srw,
    unsigned short* __restrict__ Xb,
    unsigned short* __restrict__ Wb,
    unsigned short* __restrict__ X4b,
    unsigned short* __restrict__ Vp)
{
  __shared__ float tile[32][33];
  int t = threadIdx.x;
  int bx = blockIdx.x;
  if (bx < 1600) {                 // transpose part
    int tx = t & 31, ty = t >> 5;
    int b = bx / 800;
    int rem = bx % 800;
    int c0 = (rem / 200) * 32, s0 = (rem % 200) * 32;
#pragma unroll
    for (int r = 0; r < 32; r += 8)
      tile[ty + r][tx] = x[((size_t)b * DIM + c0 + ty + r) * NQ + s0 + tx];
    __syncthreads();
#pragma unroll
    for (int r = 0; r < 32; r += 8)
      Xb[((size_t)b * NQ + s0 + ty + r) * DIM + c0 + tx] = f2bf(tile[tx][ty + r]);
    return;
  }
  int e = (bx - 1600) * 256 + t;   // 1,638,400 total
  if (e < 131072) {                // weight cast: q|k|v|proj 16384 ea | sr 65536
    const float* src; int idx;
    if (e < 16384)      { src = qw;  idx = e; }
    else if (e < 32768) { src = kw;  idx = e - 16384; }
    else if (e < 49152) { src = vw;  idx = e - 32768; }
    else if (e < 65536) { src = pw;  idx = e - 49152; }
    else                { src = srw; idx = e - 65536; }
    Wb[e] = f2bf(src[idx]);
  }
  if (e < NBATCH * HEADS * NC * 32) {   // Vp lane-16 (denominator) fill: 25600
    int cid = e >> 5;
    int pos = e & 31;
    size_t addr = (size_t)cid * 1024 + 256 + ((pos & 16) ? 512 : 0) + (pos & 15);
    Vp[addr] = 0x3F80;               // 1.0 bf16
  }
  int c4 = e & 511;
  int r = e >> 9;                    // b*1600 + m
  int b = r / 1600, m = r % 1600;
  int c = c4 >> 2, ky = (c4 >> 1) & 1, kx = c4 & 1;
  int i = m / 40, j = m % 40;
  X4b[e] = f2bf(x[((size_t)b * DIM + c) * NQ + (2 * i + ky) * 80 + 2 * j + kx]);
}

// ---------------------------------------------------------------------------
// Fused q + sr GEMM (round-7 verbatim). Block 256 = 4 waves.
// blockIdx.x < 200: q-tile of Xb (C=128) -> Qb bf16 token-major, *SCALE*log2e
// blockIdx.x >= 200: sr-tile of X4b (C=512) -> BN+ReLU -> xkvb bf16 token-major
// C/D: col o = lane&31, row s = (reg&3)+8*(reg>>2)+4*hf.
// ---------------------------------------------------------------------------
__global__ __launch_bounds__(256) void mgemm_qsr(
    const bf16_t* __restrict__ Xb, const bf16_t* __restrict__ X4b,
    const bf16_t* __restrict__ Wb,
    const float* __restrict__ q_b, const float* __restrict__ sr_b,
    unsigned short* __restrict__ Qb, unsigned short* __restrict__ xkvb,
    float sl,
    const float* __restrict__ bng, const float* __restrict__ bnb,
    const float* __restrict__ bnm, const float* __restrict__ bnv)
{
  int t = threadIdx.x;
  int ln = t & 31, hf = (t >> 5) & 1, wid = t >> 6;
  int b = blockIdx.y;
  bool isq = blockIdx.x < 200;
  int s0 = isq ? blockIdx.x * 32 : (blockIdx.x - 200) * 32;
  int S  = isq ? NQ : NKV;
  int C  = isq ? 128 : 512;
  const bf16_t* X = isq ? Xb : X4b;
  const bf16_t* W = isq ? Wb : (Wb + 65536);
  int o = wid * 32 + ln;

  const bf16_t* arow = &X[((size_t)b * S + s0 + ln) * C + hf * 8];
  const bf16_t* brow = &W[(size_t)o * C + hf * 8];
  f32x16 acc = {};
#pragma unroll 8
  for (int c0 = 0; c0 < C; c0 += 16) {
    bf16x8 af = *(const bf16x8*)&arow[c0];
    bf16x8 bf = *(const bf16x8*)&brow[c0];
    acc = __builtin_amdgcn_mfma_f32_32x32x16_bf16(af, bf, acc, 0, 0, 0);
  }

  float bv, a1, b2;
  bool relu;
  if (isq) { bv = q_b[o]; a1 = sl; b2 = 0.f; relu = false; }
  else {
    bv = sr_b[o];
    float inv = bng[o] / sqrtf(bnv[o] + BN_EPS);
    a1 = inv; b2 = bnb[o] - bnm[o] * inv; relu = true;
  }
  unsigned short* ob = isq ? Qb : xkvb;
#pragma unroll
  for (int g = 0; g < 4; ++g)
#pragma unroll
    for (int j = 0; j < 4; ++j) {
      float v = (acc[4 * g + j] + bv) * a1 + b2;
      if (relu) v = fmaxf(v, 0.f);
      int s = s0 + 8 * g + 4 * hf + j;
      ob[((size_t)b * S + s) * DIM + o] = f2bf(v);
    }
}

// ---------------------------------------------------------------------------
// Fused k + v GEMM (round-7 verbatim). blockIdx.z: 0 = k, 1 = v.
// Fragment-major epilogues (attention-coalesced):
// k -> Kp[(b*8+h)*50+chunk][s_local*16+d]
// v -> Vp[(b*8+h)*50+chunk][va:512 | vb:512] (kv-permuted identity w/ S-layout)
// ---------------------------------------------------------------------------
__global__ __launch_bounds__(256) void mgemm_kv(
    const bf16_t* __restrict__ xkvb, const bf16_t* __restrict__ Wb,
    const float* __restrict__ k_b, const float* __restrict__ v_b,
    unsigned short* __restrict__ Kp, unsigned short* __restrict__ Vp)
{
  int t = threadIdx.x;
  int ln = t & 31, hf = (t >> 5) & 1, wid = t >> 6;
  int b = blockIdx.y;
  int isv = blockIdx.z;
  int s0 = blockIdx.x * 32;
  const bf16_t* W = Wb + (isv ? 32768 : 16384);
  int o = wid * 32 + ln;

  const bf16_t* arow = &xkvb[((size_t)b * NKV + s0 + ln) * DIM + hf * 8];
  const bf16_t* brow = &W[(size_t)o * DIM + hf * 8];
  f32x16 acc = {};
#pragma unroll
  for (int c0 = 0; c0 < 128; c0 += 16) {
    bf16x8 af = *(const bf16x8*)&arow[c0];
    bf16x8 bf = *(const bf16x8*)&brow[c0];
    acc = __builtin_amdgcn_mfma_f32_32x32x16_bf16(af, bf, acc, 0, 0, 0);
  }

  int hloc = o >> 4, d = o & 15;
  if (isv) {
    float bv = v_b[o];
    size_t CB = (((size_t)b * HEADS + hloc) * NC + (s0 >> 5)) * 1024;
    uint4 w0, w1;
    w0.x = packbf2(acc[0] + bv, acc[1] + bv);
    w0.y = packbf2(acc[2] + bv, acc[3] + bv);
    w0.z = packbf2(acc[4] + bv, acc[5] + bv);
    w0.w = packbf2(acc[6] + bv, acc[7] + bv);
    w1.x = packbf2(acc[8] + bv, acc[9] + bv);
    w1.y = packbf2(acc[10] + bv, acc[11] + bv);
    w1.z = packbf2(acc[12] + bv, acc[13] + bv);
    w1.w = packbf2(acc[14] + bv, acc[15] + bv);
    *(uint4*)&Vp[CB + d * 16 + hf * 8] = w0;         // va block
    *(uint4*)&Vp[CB + 512 + d * 16 + hf * 8] = w1;   // vb block
  } else {
    float bv = k_b[o];
    size_t CB = (((size_t)b * HEADS + hloc) * NC + (s0 >> 5)) * 512;
#pragma unroll
    for (int g = 0; g < 4; ++g)
#pragma unroll
      for (int j = 0; j < 4; ++j) {
        int sl2 = 8 * g + 4 * hf + j;                // s_local row
        Kp[CB + sl2 * 16 + d] = f2bf(acc[4 * g + j] + bv);
      }
  }
}

// ---------------------------------------------------------------------------
// MFMA attention, kv-split = nsplit (round-8 loop body: no prefetch), fragment-
// major K/V. nsplit=4 -> 12800 waves (12.5/SIMD). grid (50, 8, 2*nsplit),
// block 256 (4 independent q-tiles sharing the (b,h,quarter) K/V stream).
// ---------------------------------------------------------------------------
__global__ __launch_bounds__(256, 8) void attn_split(
    const bf16_t* __restrict__ Qb, const bf16_t* __restrict__ Kp,
    const bf16_t* __restrict__ Vp, unsigned short* __restrict__ Pb,
    float* __restrict__ Lsum, int nsplit)
{
  const int t = threadIdx.x;
  const int ln = t & 31, hf = (t >> 5) & 1, wid = t >> 6;
  const int h = blockIdx.y;
  const int b = blockIdx.z & 1, quarter = blockIdx.z >> 1;
  const int q0 = blockIdx.x * 128 + wid * 32;
  const int base = NC / nsplit, rem = NC % nsplit;
  const int kcnt = base + (quarter < rem ? 1 : 0);
  const int kstart = quarter * base + (quarter < rem ? quarter : rem);
  const int slice = quarter * 2 + b;

  bf16x8 qf = *(const bf16x8*)&Qb[((size_t)b * NQ + q0 + ln) * DIM + h * 16 + hf * 8];
  const int bh = b * HEADS + h;
  const bf16_t* kc = &Kp[((size_t)bh * NC + kstart) * 512 + ln * 16 + hf * 8];
  const bf16_t* vc = &Vp[((size_t)bh * NC + kstart) * 1024 + ln * 16 + hf * 8];

  f32x16 acc = {};
  const f32x16 zero = {};

  for (int c = 0; c < kcnt; ++c) {
    bf16x8 kf = *(const bf16x8*)kc;
    bf16x8 va = *(const bf16x8*)vc;
    bf16x8 vb = *(const bf16x8*)(vc + 512);

    f32x16 S = __builtin_amdgcn_mfma_f32_32x32x16_bf16(kf, qf, zero, 0, 0, 0);

    BF8U f0, f1;
#pragma unroll
    for (int i = 0; i < 4; ++i) {
      f0.u[i] = packbf2(__builtin_amdgcn_exp2f(S[2 * i]),
                        __builtin_amdgcn_exp2f(S[2 * i + 1]));
      f1.u[i] = packbf2(__builtin_amdgcn_exp2f(S[8 + 2 * i]),
                        __builtin_amdgcn_exp2f(S[9 + 2 * i]));
    }

    acc = __builtin_amdgcn_mfma_f32_32x32x16_bf16(va, f0.v, acc, 0, 0, 0);
    acc = __builtin_amdgcn_mfma_f32_32x32x16_bf16(vb, f1.v, acc, 0, 0, 0);
    kc += 512; vc += 1024;
  }

  // acc: col q = ln, row d = (r&3)+8*(r>>2)+4*hf. Row16 (denom) = acc[8]@hf0.
  unsigned short* prow =
      &Pb[(size_t)slice * (NQ * DIM) + (size_t)(q0 + ln) * DIM + h * 16 + 4 * hf];
  uint2 w0, w1;
  w0.x = packbf2(acc[0], acc[1]); w0.y = packbf2(acc[2], acc[3]);
  w1.x = packbf2(acc[4], acc[5]); w1.y = packbf2(acc[6], acc[7]);
  *(uint2*)&prow[0] = w0;
  *(uint2*)&prow[8] = w1;
  if (!hf)
    Lsum[(size_t)slice * (HEADS * NQ) + (size_t)h * NQ + q0 + ln] = acc[8];
}

// ---------------------------------------------------------------------------
// proj_comb: fused combine (nsplit partials) + reference scramble + proj GEMM.
// As[s_local][c] = sum_q(Pq)/sum_q(Lq) at flat att index f = c*6400+(s0+sl)
// (the transpose/reshape scramble). grid (200, 2), block 256.
// ---------------------------------------------------------------------------
__global__ __launch_bounds__(256) void proj_comb(
    const unsigned short* __restrict__ Pb, const float* __restrict__ Lsum,
    const bf16_t* __restrict__ Wb, const float* __restrict__ p_b,
    float* __restrict__ Out, int nsplit)
{
  __shared__ __align__(16) unsigned short As[32][136];
  int t = threadIdx.x;
  int b = blockIdx.y;
  int s0 = blockIdx.x * 32;

  {
    int tx = t & 31, cg = t >> 5;          // lane sweeps s (coalesced in f)
#pragma unroll
    for (int it = 0; it < 16; ++it) {
      int c = cg * 16 + it;
      int f = c * NQ + s0 + tx;            // flat att index = n*128 + h*16+d
      int n = f >> 7, hh = (f >> 4) & 7;
      float ps = 0.f, L = 0.f;
      for (int qq = 0; qq < nsplit; ++qq) {
        int sl2 = qq * 2 + b;
        ps += __uint_as_float((unsigned)Pb[(size_t)sl2 * (NQ * DIM) + f] << 16);
        L += Lsum[(size_t)sl2 * (HEADS * NQ) + (size_t)hh * NQ + n];
      }
      As[tx][c] = f2bf(ps / L);
    }
  }
  __syncthreads();

  int ln = t & 31, hf = (t >> 5) & 1, wid = t >> 6;
  int o = wid * 32 + ln;
  const bf16_t* brow = &Wb[49152 + (size_t)o * DIM + hf * 8];
  const unsigned short* arow = &As[ln][hf * 8];
  f32x16 acc = {};
#pragma unroll
  for (int c0 = 0; c0 < 128; c0 += 16) {
    bf16x8 af = *(const bf16x8*)&arow[c0];
    bf16x8 bf = *(const bf16x8*)&brow[c0];
    acc = __builtin_amdgcn_mfma_f32_32x32x16_bf16(af, bf, acc, 0, 0, 0);
  }
  float bv = p_b[o];
  float* obase = &Out[((size_t)b * DIM + o) * NQ + s0 + 4 * hf];
#pragma unroll
  for (int g = 0; g < 4; ++g) {
    float4 r;
    r.x = acc[4 * g + 0] + bv; r.y = acc[4 * g + 1] + bv;
    r.z = acc[4 * g + 2] + bv; r.w = acc[4 * g + 3] + bv;
    *(float4*)&obase[8 * g] = r;
  }
}

// ---------------------------------------------------------------------------
extern "C" void kernel_launch(void* const* d_in, const int* in_sizes, int n_in,
                              void* d_out, int out_size, void* d_ws, size_t ws_size,
                              hipStream_t stream)
{
  const float* x    = (const float*)d_in[0];
  const float* q_w  = (const float*)d_in[1];
  const float* q_b  = (const float*)d_in[2];
  const float* k_w  = (const float*)d_in[3];
  const float* k_b  = (const float*)d_in[4];
  const float* v_w  = (const float*)d_in[5];
  const float* v_b  = (const float*)d_in[6];
  const float* sr_w = (const float*)d_in[7];
  const float* sr_b = (const float*)d_in[8];
  const float* bng  = (const float*)d_in[9];
  const float* bnb  = (const float*)d_in[10];
  const float* bnm  = (const float*)d_in[11];
  const float* bnv  = (const float*)d_in[12];
  const float* p_w  = (const float*)d_in[13];
  const float* p_b  = (const float*)d_in[14];
  float* out = (float*)d_out;

  float* ws = (float*)d_ws;
  // f32-slot layout, NO aliasing (ws is 256+ MB; we use ~28.2 MB):
  bf16_t* Xb   = (bf16_t*)(ws);             // [0, 819200)
  bf16_t* X4b  = (bf16_t*)(ws + 819200);    // [819200, 1638400)
  bf16_t* xkvb = (bf16_t*)(ws + 1638400);   // [1638400, 1843200)
  bf16_t* Qb   = (bf16_t*)(ws + 1843200);   // [1843200, 2662400)
  bf16_t* Kp   = (bf16_t*)(ws + 2662400);   // [2662400, 2867200)
  bf16_t* Vp   = (bf16_t*)(ws + 2867200);   // [2867200, 3276800)
  float*  Lsum = ws + 3276800;              // [3276800, 3686400) (8 slices max)
  bf16_t* Wb   = (bf16_t*)(ws + 3686400);   // [3686400, 3751936)
  bf16_t* Pb   = (bf16_t*)(ws + 3751936);   // [3751936, +nsplit*819200)

  // kv-split: 4 if workspace allows (~28.2 MB), else 2. ws_size is constant
  // per session -> identical behavior every call (graph-safe).
  const int nsplit = (ws_size >= (size_t)7028736 * 4) ? 4 : 2;

  const float sl = 0.25f * LOG2E;  // SCALE * log2(e) folded into Q

  // 1. transpose + im2col + weight cast + Vp denom fill (fused)
  prep_all<<<dim3(8000), dim3(256), 0, stream>>>(
      x, q_w, k_w, v_w, p_w, sr_w,
      (unsigned short*)Xb, (unsigned short*)Wb,
      (unsigned short*)X4b, (unsigned short*)Vp);

  // 2. q (blocks 0-199) + sr conv/BN/ReLU (blocks 200-249)
  mgemm_qsr<<<dim3(250, NBATCH), dim3(256), 0, stream>>>(
      Xb, X4b, Wb, q_b, sr_b, (unsigned short*)Qb, (unsigned short*)xkvb,
      sl, bng, bnb, bnm, bnv);

  // 3. k (z=0) + v (z=1), fragment-major epilogues
  mgemm_kv<<<dim3(NKV / 32, NBATCH, 2), dim3(256), 0, stream>>>(
      xkvb, Wb, k_b, v_b, (unsigned short*)Kp, (unsigned short*)Vp);

  // 4. attention partials (kv-split = nsplit)
  attn_split<<<dim3(NQ / 128, HEADS, 2 * nsplit), dim3(256), 0, stream>>>(
      Qb, Kp, Vp, (unsigned short*)Pb, Lsum, nsplit);

  // 5. combine + scramble + proj -> f32 chan-major final output (B,128,80,80)
  proj_comb<<<dim3(200, NBATCH), dim3(256), 0, stream>>>(
      (const unsigned short*)Pb, Lsum, Wb, p_b, out, nsplit);
}

// Round 11
// 162.283 us; speedup vs baseline: 1.0503x; 1.0276x over previous
//
#include <hip/hip_runtime.h>
#include <hip/hip_bf16.h>
#include <cmath>

#define DIM 128
#define HEADS 8
#define NBATCH 2
#define NQ 6400   /* 80*80 */
#define NKV 1600  /* 40*40 */
#define NC 50     /* kv chunks of 32 */
#define BN_EPS 1e-5f
#define LOG2E 1.4426950408889634f

typedef __bf16 bf16_t;
typedef __attribute__((ext_vector_type(8))) __bf16 bf16x8;
typedef __attribute__((ext_vector_type(16))) float f32x16;

union BF8U { bf16x8 v; unsigned u[4]; };

// pack two f32 -> packed bf16 (a->lo, b->hi); lowers to v_cvt_pk_bf16_f32 (RNE)
__device__ inline unsigned packbf2(float a, float b) {
  union { __hip_bfloat162 v; unsigned u; } r;
  r.v = __float22bfloat162_rn(make_float2(a, b));
  return r.u;
}

__device__ inline unsigned short f2bf(float v) {
  unsigned u = __float_as_uint(v);
  return (unsigned short)((u + 0x7FFFu + ((u >> 16) & 1u)) >> 16);
}

// ---------------------------------------------------------------------------
// prep_all (round-7 verbatim): fused transpose + im2col + weight cast + Vp
// denominator fill.
// blocks [0,1600):  x (B,128,6400) f32 -> Xb (B,6400,128) bf16 (LDS tile)
// blocks [1600,8000): e-indexed: im2col X4b[b][m][c4] + Wb cast + Vp lane-16
// ---------------------------------------------------------------------------
__global__ __launch_bounds__(256) void prep_all(
    const float* __restrict__ x,
    const float* __restrict__ qw, const float* __restrict__ kw,
    const float* __restrict__ vw, const float* __restrict__ pw,
    const float* __restrict__ srw,
    unsigned short* __restrict__ Xb,
    unsigned short* __restrict__ Wb,
    unsigned short* __restrict__ X4b,
    unsigned short* __restrict__ Vp)
{
  __shared__ float tile[32][33];
  int t = threadIdx.x;
  int bx = blockIdx.x;
  if (bx < 1600) {                 // transpose part
    int tx = t & 31, ty = t >> 5;
    int b = bx / 800;
    int rem = bx % 800;
    int c0 = (rem / 200) * 32, s0 = (rem % 200) * 32;
#pragma unroll
    for (int r = 0; r < 32; r += 8)
      tile[ty + r][tx] = x[((size_t)b * DIM + c0 + ty + r) * NQ + s0 + tx];
    __syncthreads();
#pragma unroll
    for (int r = 0; r < 32; r += 8)
      Xb[((size_t)b * NQ + s0 + ty + r) * DIM + c0 + tx] = f2bf(tile[tx][ty + r]);
    return;
  }
  int e = (bx - 1600) * 256 + t;   // 1,638,400 total
  if (e < 131072) {                // weight cast: q|k|v|proj 16384 ea | sr 65536
    const float* src; int idx;
    if (e < 16384)      { src = qw;  idx = e; }
    else if (e < 32768) { src = kw;  idx = e - 16384; }
    else if (e < 49152) { src = vw;  idx = e - 32768; }
    else if (e < 65536) { src = pw;  idx = e - 49152; }
    else                { src = srw; idx = e - 65536; }
    Wb[e] = f2bf(src[idx]);
  }
  if (e < NBATCH * HEADS * NC * 32) {   // Vp lane-16 (denominator) fill: 25600
    int cid = e >> 5;
    int pos = e & 31;
    size_t addr = (size_t)cid * 1024 + 256 + ((pos & 16) ? 512 : 0) + (pos & 15);
    Vp[addr] = 0x3F80;               // 1.0 bf16
  }
  int c4 = e & 511;
  int r = e >> 9;                    // b*1600 + m
  int b = r / 1600, m = r % 1600;
  int c = c4 >> 2, ky = (c4 >> 1) & 1, kx = c4 & 1;
  int i = m / 40, j = m % 40;
  X4b[e] = f2bf(x[((size_t)b * DIM + c) * NQ + (2 * i + ky) * 80 + 2 * j + kx]);
}

// ---------------------------------------------------------------------------
// Fused q + (sr -> k -> v) GEMM. Block 256 = 4 waves; wave w owns o-tile w*32.
// blocks [0,50):    sr tile (C=512) -> BN+ReLU -> LDS (32 tok x 128 ch)
//                   -> sync -> k GEMM + v GEMM off LDS with fragment-major
//                   epilogues (Kp / Vp, attention-coalesced). No xkvb global
//                   round-trip, no separate kv kernel. Scheduled first (3x
//                   longer than q blocks) to avoid tail imbalance.
// blocks [50,250):  q tile of Xb (C=128) -> Qb bf16 token-major, *SCALE*log2e
// C/D: col o = lane&31, row s = (reg&3)+8*(reg>>2)+4*hf.
// k -> Kp[(b*8+h)*50+chunk][s_local*16+d]
// v -> Vp[(b*8+h)*50+chunk][va:512 | vb:512] (kv-permuted identity w/ S-layout)
// ---------------------------------------------------------------------------
__global__ __launch_bounds__(256) void mgemm_qsrkv(
    const bf16_t* __restrict__ Xb, const bf16_t* __restrict__ X4b,
    const bf16_t* __restrict__ Wb,
    const float* __restrict__ q_b, const float* __restrict__ sr_b,
    const float* __restrict__ k_b, const float* __restrict__ v_b,
    const float* __restrict__ bng, const float* __restrict__ bnb,
    const float* __restrict__ bnm, const float* __restrict__ bnv,
    unsigned short* __restrict__ Qb,
    unsigned short* __restrict__ Kp, unsigned short* __restrict__ Vp,
    float sl)
{
  __shared__ __align__(16) unsigned short xs[32][136];
  int t = threadIdx.x;
  int ln = t & 31, hf = (t >> 5) & 1, wid = t >> 6;
  int b = blockIdx.y;
  int o = wid * 32 + ln;

  if (blockIdx.x < 50) {             // ---- sr -> k -> v part ----
    int s0 = blockIdx.x * 32;
    const bf16_t* arow = &X4b[((size_t)b * NKV + s0 + ln) * 512 + hf * 8];
    const bf16_t* brow = &Wb[65536 + (size_t)o * 512 + hf * 8];
    f32x16 acc = {};
#pragma unroll 8
    for (int c0 = 0; c0 < 512; c0 += 16) {
      bf16x8 af = *(const bf16x8*)&arow[c0];
      bf16x8 bf = *(const bf16x8*)&brow[c0];
      acc = __builtin_amdgcn_mfma_f32_32x32x16_bf16(af, bf, acc, 0, 0, 0);
    }
    float bv = sr_b[o];
    float inv = bng[o] / sqrtf(bnv[o] + BN_EPS);
    float b2 = bnb[o] - bnm[o] * inv;
#pragma unroll
    for (int g = 0; g < 4; ++g)
#pragma unroll
      for (int j = 0; j < 4; ++j) {
        int s = 8 * g + 4 * hf + j;
        xs[s][o] = f2bf(fmaxf((acc[4 * g + j] + bv) * inv + b2, 0.f));
      }
    __syncthreads();

    // k + v GEMMs (C=128) off the LDS tile
    const unsigned short* ar2 = &xs[ln][hf * 8];
    const bf16_t* kbrow = &Wb[16384 + (size_t)o * DIM + hf * 8];
    const bf16_t* vbrow = &Wb[32768 + (size_t)o * DIM + hf * 8];
    f32x16 ka = {}, va = {};
#pragma unroll
    for (int c0 = 0; c0 < 128; c0 += 16) {
      bf16x8 af = *(const bf16x8*)&ar2[c0];
      bf16x8 kb = *(const bf16x8*)&kbrow[c0];
      bf16x8 vb = *(const bf16x8*)&vbrow[c0];
      ka = __builtin_amdgcn_mfma_f32_32x32x16_bf16(af, kb, ka, 0, 0, 0);
      va = __builtin_amdgcn_mfma_f32_32x32x16_bf16(af, vb, va, 0, 0, 0);
    }
    int hloc = o >> 4, d = o & 15;
    {
      float kb2 = k_b[o];
      size_t CB = (((size_t)b * HEADS + hloc) * NC + (s0 >> 5)) * 512;
#pragma unroll
      for (int g = 0; g < 4; ++g)
#pragma unroll
        for (int j = 0; j < 4; ++j) {
          int sl2 = 8 * g + 4 * hf + j;              // s_local row
          Kp[CB + sl2 * 16 + d] = f2bf(ka[4 * g + j] + kb2);
        }
    }
    {
      float vb2 = v_b[o];
      size_t CB = (((size_t)b * HEADS + hloc) * NC + (s0 >> 5)) * 1024;
      uint4 w0, w1;
      w0.x = packbf2(va[0] + vb2, va[1] + vb2);
      w0.y = packbf2(va[2] + vb2, va[3] + vb2);
      w0.z = packbf2(va[4] + vb2, va[5] + vb2);
      w0.w = packbf2(va[6] + vb2, va[7] + vb2);
      w1.x = packbf2(va[8] + vb2, va[9] + vb2);
      w1.y = packbf2(va[10] + vb2, va[11] + vb2);
      w1.z = packbf2(va[12] + vb2, va[13] + vb2);
      w1.w = packbf2(va[14] + vb2, va[15] + vb2);
      *(uint4*)&Vp[CB + d * 16 + hf * 8] = w0;       // va block
      *(uint4*)&Vp[CB + 512 + d * 16 + hf * 8] = w1; // vb block
    }
  } else {                           // ---- q part (C = 128) ----
    int s0 = (blockIdx.x - 50) * 32;
    const bf16_t* arow = &Xb[((size_t)b * NQ + s0 + ln) * DIM + hf * 8];
    const bf16_t* brow = &Wb[(size_t)o * DIM + hf * 8];
    f32x16 acc = {};
#pragma unroll
    for (int c0 = 0; c0 < 128; c0 += 16) {
      bf16x8 af = *(const bf16x8*)&arow[c0];
      bf16x8 bf = *(const bf16x8*)&brow[c0];
      acc = __builtin_amdgcn_mfma_f32_32x32x16_bf16(af, bf, acc, 0, 0, 0);
    }
    float bv = q_b[o];
#pragma unroll
    for (int g = 0; g < 4; ++g)
#pragma unroll
      for (int j = 0; j < 4; ++j) {
        int s = s0 + 8 * g + 4 * hf + j;
        Qb[((size_t)b * NQ + s) * DIM + o] = f2bf((acc[4 * g + j] + bv) * sl);
      }
  }
}

// ---------------------------------------------------------------------------
// MFMA attention (round-7 verbatim): kv-split=2, fragment-major K/V, register
// prefetch. Block 256 = 4 independent 32-q tiles sharing the (b,h,half) K/V
// stream. grid (50, 8, 4): z = b + 2*half.
// ---------------------------------------------------------------------------
__global__ __launch_bounds__(256) void attn_split(const bf16_t* __restrict__ Qb,
                                                  const bf16_t* __restrict__ Kp,
                                                  const bf16_t* __restrict__ Vp,
                                                  unsigned short* __restrict__ Pb,
                                                  float* __restrict__ Lsum)
{
  const int t = threadIdx.x;
  const int ln = t & 31, hf = (t >> 5) & 1, wid = t >> 6;
  const int h = blockIdx.y;
  const int b = blockIdx.z & 1, half = blockIdx.z >> 1;
  const int q0 = blockIdx.x * 128 + wid * 32;

  bf16x8 qf = *(const bf16x8*)&Qb[((size_t)b * NQ + q0 + ln) * DIM + h * 16 + hf * 8];
  const int bh = b * HEADS + h;
  const bf16_t* kc = &Kp[((size_t)bh * NC + half * 25) * 512 + ln * 16 + hf * 8];
  const bf16_t* vc = &Vp[((size_t)bh * NC + half * 25) * 1024 + ln * 16 + hf * 8];

  f32x16 acc = {};
  const f32x16 zero = {};

  bf16x8 kf = *(const bf16x8*)kc;
  bf16x8 va = *(const bf16x8*)vc;
  bf16x8 vb = *(const bf16x8*)(vc + 512);

  for (int c = 0; c < 25; ++c) {
    int cn = (c < 24) ? c + 1 : c;   // prefetch (last iter re-reads, discarded)
    bf16x8 kf2 = *(const bf16x8*)(kc + cn * 512);
    bf16x8 va2 = *(const bf16x8*)(vc + cn * 1024);
    bf16x8 vb2 = *(const bf16x8*)(vc + cn * 1024 + 512);

    f32x16 S = __builtin_amdgcn_mfma_f32_32x32x16_bf16(kf, qf, zero, 0, 0, 0);

    BF8U f0, f1;
#pragma unroll
    for (int i = 0; i < 4; ++i) {
      f0.u[i] = packbf2(__builtin_amdgcn_exp2f(S[2 * i]),
                        __builtin_amdgcn_exp2f(S[2 * i + 1]));
      f1.u[i] = packbf2(__builtin_amdgcn_exp2f(S[8 + 2 * i]),
                        __builtin_amdgcn_exp2f(S[9 + 2 * i]));
    }

    acc = __builtin_amdgcn_mfma_f32_32x32x16_bf16(va, f0.v, acc, 0, 0, 0);
    acc = __builtin_amdgcn_mfma_f32_32x32x16_bf16(vb, f1.v, acc, 0, 0, 0);
    kf = kf2; va = va2; vb = vb2;
  }

  // acc: col q = ln, row d = (r&3)+8*(r>>2)+4*hf. Row16 (denom) = acc[8]@hf0.
  unsigned short* prow =
      &Pb[(size_t)(half * 2 + b) * (NQ * DIM) + (size_t)(q0 + ln) * DIM + h * 16 + 4 * hf];
  uint2 w0, w1;
  w0.x = packbf2(acc[0], acc[1]); w0.y = packbf2(acc[2], acc[3]);
  w1.x = packbf2(acc[4], acc[5]); w1.y = packbf2(acc[6], acc[7]);
  *(uint2*)&prow[0] = w0;
  *(uint2*)&prow[8] = w1;
  if (!hf)
    Lsum[(size_t)(half * 2 + b) * (HEADS * NQ) + (size_t)h * NQ + q0 + ln] = acc[8];
}

// ---------------------------------------------------------------------------
// proj_comb (round-7 verbatim): fused combine (2 halves) + reference scramble
// + proj GEMM. As[s_local][c] = sum(P)/sum(L) at flat att index f=c*6400+s
// (the transpose/reshape scramble). grid (200, 2), block 256.
// ---------------------------------------------------------------------------
__global__ __launch_bounds__(256) void proj_comb(
    const unsigned short* __restrict__ Pb, const float* __restrict__ Lsum,
    const bf16_t* __restrict__ Wb, const float* __restrict__ p_b,
    float* __restrict__ Out)
{
  __shared__ __align__(16) unsigned short As[32][136];
  int t = threadIdx.x;
  int b = blockIdx.y;
  int s0 = blockIdx.x * 32;

  {
    int tx = t & 31, cg = t >> 5;          // lane sweeps s (coalesced in f)
#pragma unroll
    for (int it = 0; it < 16; ++it) {
      int c = cg * 16 + it;
      int f = c * NQ + s0 + tx;            // flat att index = n*128 + h*16+d
      int n = f >> 7, hh = (f >> 4) & 7;
      float p0 = __uint_as_float((unsigned)Pb[(size_t)b * (NQ * DIM) + f] << 16);
      float p1 = __uint_as_float((unsigned)Pb[(size_t)(2 + b) * (NQ * DIM) + f] << 16);
      float L = Lsum[(size_t)b * (HEADS * NQ) + (size_t)hh * NQ + n] +
                Lsum[(size_t)(2 + b) * (HEADS * NQ) + (size_t)hh * NQ + n];
      As[tx][c] = f2bf((p0 + p1) / L);
    }
  }
  __syncthreads();

  int ln = t & 31, hf = (t >> 5) & 1, wid = t >> 6;
  int o = wid * 32 + ln;
  const bf16_t* brow = &Wb[49152 + (size_t)o * DIM + hf * 8];
  const unsigned short* arow = &As[ln][hf * 8];
  f32x16 acc = {};
#pragma unroll
  for (int c0 = 0; c0 < 128; c0 += 16) {
    bf16x8 af = *(const bf16x8*)&arow[c0];
    bf16x8 bf = *(const bf16x8*)&brow[c0];
    acc = __builtin_amdgcn_mfma_f32_32x32x16_bf16(af, bf, acc, 0, 0, 0);
  }
  float bv = p_b[o];
  float* obase = &Out[((size_t)b * DIM + o) * NQ + s0 + 4 * hf];
#pragma unroll
  for (int g = 0; g < 4; ++g) {
    float4 r;
    r.x = acc[4 * g + 0] + bv; r.y = acc[4 * g + 1] + bv;
    r.z = acc[4 * g + 2] + bv; r.w = acc[4 * g + 3] + bv;
    *(float4*)&obase[8 * g] = r;
  }
}

// ---------------------------------------------------------------------------
extern "C" void kernel_launch(void* const* d_in, const int* in_sizes, int n_in,
                              void* d_out, int out_size, void* d_ws, size_t ws_size,
                              hipStream_t stream)
{
  const float* x    = (const float*)d_in[0];
  const float* q_w  = (const float*)d_in[1];
  const float* q_b  = (const float*)d_in[2];
  const float* k_w  = (const float*)d_in[3];
  const float* k_b  = (const float*)d_in[4];
  const float* v_w  = (const float*)d_in[5];
  const float* v_b  = (const float*)d_in[6];
  const float* sr_w = (const float*)d_in[7];
  const float* sr_b = (const float*)d_in[8];
  const float* bng  = (const float*)d_in[9];
  const float* bnb  = (const float*)d_in[10];
  const float* bnm  = (const float*)d_in[11];
  const float* bnv  = (const float*)d_in[12];
  const float* p_w  = (const float*)d_in[13];
  const float* p_b  = (const float*)d_in[14];
  float* out = (float*)d_out;

  float* ws = (float*)d_ws;
  // f32-slot layout, no aliasing (~19.9 MB of the 256+ MB ws):
  bf16_t* Xb   = (bf16_t*)(ws);             // [0, 819200)
  bf16_t* X4b  = (bf16_t*)(ws + 819200);    // [819200, 1638400)
  bf16_t* Qb   = (bf16_t*)(ws + 1638400);   // [1638400, 2457600)
  bf16_t* Kp   = (bf16_t*)(ws + 2457600);   // [2457600, 2662400)
  bf16_t* Vp   = (bf16_t*)(ws + 2662400);   // [2662400, 3072000)
  float*  Lsum = ws + 3072000;              // [3072000, 3276800)
  bf16_t* Wb   = (bf16_t*)(ws + 3276800);   // [3276800, 3342336)
  bf16_t* Pb   = (bf16_t*)(ws + 3342336);   // [3342336, 4980736) 4 slices

  const float sl = 0.25f * LOG2E;  // SCALE * log2(e) folded into Q

  // 1. transpose + im2col + weight cast + Vp denom fill (fused)
  prep_all<<<dim3(8000), dim3(256), 0, stream>>>(
      x, q_w, k_w, v_w, p_w, sr_w,
      (unsigned short*)Xb, (unsigned short*)Wb,
      (unsigned short*)X4b, (unsigned short*)Vp);

  // 2. sr->k->v (blocks 0-49, LDS-fused) + q (blocks 50-249)
  mgemm_qsrkv<<<dim3(250, NBATCH), dim3(256), 0, stream>>>(
      Xb, X4b, Wb, q_b, sr_b, k_b, v_b, bng, bnb, bnm, bnv,
      (unsigned short*)Qb, (unsigned short*)Kp, (unsigned short*)Vp, sl);

  // 3. attention partials (kv-split = 2, prefetch)
  attn_split<<<dim3(NQ / 128, HEADS, 4), dim3(256), 0, stream>>>(
      Qb, Kp, Vp, (unsigned short*)Pb, Lsum);

  // 4. combine + scramble + proj -> f32 chan-major final output (B,128,80,80)
  proj_comb<<<dim3(200, NBATCH), dim3(256), 0, stream>>>(
      (const unsigned short*)Pb, Lsum, Wb, p_b, out);
}

// Round 12
// 155.581 us; speedup vs baseline: 1.0955x; 1.0431x over previous
//
#include <hip/hip_runtime.h>
#include <hip/hip_bf16.h>
#include <cmath>

#define DIM 128
#define HEADS 8
#define NBATCH 2
#define NQ 6400   /* 80*80 */
#define NKV 1600  /* 40*40 */
#define NC 50     /* kv chunks of 32 */
#define BN_EPS 1e-5f
#define LOG2E 1.4426950408889634f

typedef __bf16 bf16_t;
typedef __attribute__((ext_vector_type(8))) __bf16 bf16x8;
typedef __attribute__((ext_vector_type(16))) float f32x16;

union BF8U { bf16x8 v; unsigned u[4]; };

// pack two f32 -> packed bf16 (a->lo, b->hi); lowers to v_cvt_pk_bf16_f32 (RNE)
__device__ inline unsigned packbf2(float a, float b) {
  union { __hip_bfloat162 v; unsigned u; } r;
  r.v = __float22bfloat162_rn(make_float2(a, b));
  return r.u;
}

__device__ inline unsigned short f2bf(float v) {
  unsigned u = __float_as_uint(v);
  return (unsigned short)((u + 0x7FFFu + ((u >> 16) & 1u)) >> 16);
}

// ---------------------------------------------------------------------------
// prep_all: fused transpose + im2col + weight cast + Vp denominator fill.
// blocks [0,1600):  x (B,128,6400) f32 -> Xb (B,6400,128) bf16 (LDS tile)
// blocks [1600,8000): e-indexed: im2col X4b[b][m][c4] + Wb cast + Vp lane-16
// ---------------------------------------------------------------------------
__global__ __launch_bounds__(256) void prep_all(
    const float* __restrict__ x,
    const float* __restrict__ qw, const float* __restrict__ kw,
    const float* __restrict__ vw, const float* __restrict__ pw,
    const float* __restrict__ srw,
    unsigned short* __restrict__ Xb,
    unsigned short* __restrict__ Wb,
    unsigned short* __restrict__ X4b,
    unsigned short* __restrict__ Vp)
{
  __shared__ float tile[32][33];
  int t = threadIdx.x;
  int bx = blockIdx.x;
  if (bx < 1600) {                 // transpose part
    int tx = t & 31, ty = t >> 5;
    int b = bx / 800;
    int rem = bx % 800;
    int c0 = (rem / 200) * 32, s0 = (rem % 200) * 32;
#pragma unroll
    for (int r = 0; r < 32; r += 8)
      tile[ty + r][tx] = x[((size_t)b * DIM + c0 + ty + r) * NQ + s0 + tx];
    __syncthreads();
#pragma unroll
    for (int r = 0; r < 32; r += 8)
      Xb[((size_t)b * NQ + s0 + ty + r) * DIM + c0 + tx] = f2bf(tile[tx][ty + r]);
    return;
  }
  int e = (bx - 1600) * 256 + t;   // 1,638,400 total
  if (e < 131072) {                // weight cast: q|k|v|proj 16384 ea | sr 65536
    const float* src; int idx;
    if (e < 16384)      { src = qw;  idx = e; }
    else if (e < 32768) { src = kw;  idx = e - 16384; }
    else if (e < 49152) { src = vw;  idx = e - 32768; }
    else if (e < 65536) { src = pw;  idx = e - 49152; }
    else                { src = srw; idx = e - 65536; }
    Wb[e] = f2bf(src[idx]);
  }
  if (e < NBATCH * HEADS * NC * 32) {   // Vp lane-16 (denominator) fill: 25600
    int cid = e >> 5;
    int pos = e & 31;
    size_t addr = (size_t)cid * 1024 + 256 + ((pos & 16) ? 512 : 0) + (pos & 15);
    Vp[addr] = 0x3F80;               // 1.0 bf16
  }
  int c4 = e & 511;
  int r = e >> 9;                    // b*1600 + m
  int b = r / 1600, m = r % 1600;
  int c = c4 >> 2, ky = (c4 >> 1) & 1, kx = c4 & 1;
  int i = m / 40, j = m % 40;
  X4b[e] = f2bf(x[((size_t)b * DIM + c) * NQ + (2 * i + ky) * 80 + 2 * j + kx]);
}

// ---------------------------------------------------------------------------
// Fused q + (sr -> k -> v) GEMM (round-11 verbatim). Block 256 = 4 waves.
// blocks [0,50):    sr tile (C=512) -> BN+ReLU -> LDS -> k GEMM + v GEMM with
//                   fragment-major Kp/Vp epilogues.
// blocks [50,250):  q tile of Xb (C=128) -> Qb bf16 token-major, *SCALE*log2e
// ---------------------------------------------------------------------------
__global__ __launch_bounds__(256) void mgemm_qsrkv(
    const bf16_t* __restrict__ Xb, const bf16_t* __restrict__ X4b,
    const bf16_t* __restrict__ Wb,
    const float* __restrict__ q_b, const float* __restrict__ sr_b,
    const float* __restrict__ k_b, const float* __restrict__ v_b,
    const float* __restrict__ bng, const float* __restrict__ bnb,
    const float* __restrict__ bnm, const float* __restrict__ bnv,
    unsigned short* __restrict__ Qb,
    unsigned short* __restrict__ Kp, unsigned short* __restrict__ Vp,
    float sl)
{
  __shared__ __align__(16) unsigned short xs[32][136];
  int t = threadIdx.x;
  int ln = t & 31, hf = (t >> 5) & 1, wid = t >> 6;
  int b = blockIdx.y;
  int o = wid * 32 + ln;

  if (blockIdx.x < 50) {             // ---- sr -> k -> v part ----
    int s0 = blockIdx.x * 32;
    const bf16_t* arow = &X4b[((size_t)b * NKV + s0 + ln) * 512 + hf * 8];
    const bf16_t* brow = &Wb[65536 + (size_t)o * 512 + hf * 8];
    f32x16 acc = {};
#pragma unroll 8
    for (int c0 = 0; c0 < 512; c0 += 16) {
      bf16x8 af = *(const bf16x8*)&arow[c0];
      bf16x8 bf = *(const bf16x8*)&brow[c0];
      acc = __builtin_amdgcn_mfma_f32_32x32x16_bf16(af, bf, acc, 0, 0, 0);
    }
    float bv = sr_b[o];
    float inv = bng[o] / sqrtf(bnv[o] + BN_EPS);
    float b2 = bnb[o] - bnm[o] * inv;
#pragma unroll
    for (int g = 0; g < 4; ++g)
#pragma unroll
      for (int j = 0; j < 4; ++j) {
        int s = 8 * g + 4 * hf + j;
        xs[s][o] = f2bf(fmaxf((acc[4 * g + j] + bv) * inv + b2, 0.f));
      }
    __syncthreads();

    // k + v GEMMs (C=128) off the LDS tile
    const unsigned short* ar2 = &xs[ln][hf * 8];
    const bf16_t* kbrow = &Wb[16384 + (size_t)o * DIM + hf * 8];
    const bf16_t* vbrow = &Wb[32768 + (size_t)o * DIM + hf * 8];
    f32x16 ka = {}, va = {};
#pragma unroll
    for (int c0 = 0; c0 < 128; c0 += 16) {
      bf16x8 af = *(const bf16x8*)&ar2[c0];
      bf16x8 kb = *(const bf16x8*)&kbrow[c0];
      bf16x8 vb = *(const bf16x8*)&vbrow[c0];
      ka = __builtin_amdgcn_mfma_f32_32x32x16_bf16(af, kb, ka, 0, 0, 0);
      va = __builtin_amdgcn_mfma_f32_32x32x16_bf16(af, vb, va, 0, 0, 0);
    }
    int hloc = o >> 4, d = o & 15;
    {
      float kb2 = k_b[o];
      size_t CB = (((size_t)b * HEADS + hloc) * NC + (s0 >> 5)) * 512;
#pragma unroll
      for (int g = 0; g < 4; ++g)
#pragma unroll
        for (int j = 0; j < 4; ++j) {
          int sl2 = 8 * g + 4 * hf + j;              // s_local row
          Kp[CB + sl2 * 16 + d] = f2bf(ka[4 * g + j] + kb2);
        }
    }
    {
      float vb2 = v_b[o];
      size_t CB = (((size_t)b * HEADS + hloc) * NC + (s0 >> 5)) * 1024;
      uint4 w0, w1;
      w0.x = packbf2(va[0] + vb2, va[1] + vb2);
      w0.y = packbf2(va[2] + vb2, va[3] + vb2);
      w0.z = packbf2(va[4] + vb2, va[5] + vb2);
      w0.w = packbf2(va[6] + vb2, va[7] + vb2);
      w1.x = packbf2(va[8] + vb2, va[9] + vb2);
      w1.y = packbf2(va[10] + vb2, va[11] + vb2);
      w1.z = packbf2(va[12] + vb2, va[13] + vb2);
      w1.w = packbf2(va[14] + vb2, va[15] + vb2);
      *(uint4*)&Vp[CB + d * 16 + hf * 8] = w0;       // va block
      *(uint4*)&Vp[CB + 512 + d * 16 + hf * 8] = w1; // vb block
    }
  } else {                           // ---- q part (C = 128) ----
    int s0 = (blockIdx.x - 50) * 32;
    const bf16_t* arow = &Xb[((size_t)b * NQ + s0 + ln) * DIM + hf * 8];
    const bf16_t* brow = &Wb[(size_t)o * DIM + hf * 8];
    f32x16 acc = {};
#pragma unroll
    for (int c0 = 0; c0 < 128; c0 += 16) {
      bf16x8 af = *(const bf16x8*)&arow[c0];
      bf16x8 bf = *(const bf16x8*)&brow[c0];
      acc = __builtin_amdgcn_mfma_f32_32x32x16_bf16(af, bf, acc, 0, 0, 0);
    }
    float bv = q_b[o];
#pragma unroll
    for (int g = 0; g < 4; ++g)
#pragma unroll
      for (int j = 0; j < 4; ++j) {
        int s = s0 + 8 * g + 4 * hf + j;
        Qb[((size_t)b * NQ + s) * DIM + o] = f2bf((acc[4 * g + j] + bv) * sl);
      }
  }
}

// ---------------------------------------------------------------------------
// MFMA attention, SOFTWARE-PIPELINED: kv-split=2, fragment-major K/V.
// Per chunk the serial chain load->S->exp->PV is broken up:
//  - fragments prefetched 2 chunks ahead (L2 latency covered),
//  - S for chunk c+1 computed WHILE chunk c's exp/PV runs (S-MFMA latency
//    off the critical path),
//  - dual accumulators make the two PV MFMAs independent.
// grid (50, 8, 4): z = b + 2*half. block 256 (4 indep q-tiles, shared K/V).
// ---------------------------------------------------------------------------
__global__ __launch_bounds__(256, 4) void attn_split(
    const bf16_t* __restrict__ Qb, const bf16_t* __restrict__ Kp,
    const bf16_t* __restrict__ Vp, unsigned short* __restrict__ Pb,
    float* __restrict__ Lsum)
{
  const int t = threadIdx.x;
  const int ln = t & 31, hf = (t >> 5) & 1, wid = t >> 6;
  const int h = blockIdx.y;
  const int b = blockIdx.z & 1, half = blockIdx.z >> 1;
  const int q0 = blockIdx.x * 128 + wid * 32;

  bf16x8 qf = *(const bf16x8*)&Qb[((size_t)b * NQ + q0 + ln) * DIM + h * 16 + hf * 8];
  const int bh = b * HEADS + h;
  const bf16_t* kc = &Kp[((size_t)bh * NC + half * 25) * 512 + ln * 16 + hf * 8];
  const bf16_t* vc = &Vp[((size_t)bh * NC + half * 25) * 1024 + ln * 16 + hf * 8];

  f32x16 acc0 = {}, acc1 = {};
  const f32x16 zero = {};

  // fragment sets for chunks 0 and 1
  bf16x8 kf0 = *(const bf16x8*)kc;
  bf16x8 va0 = *(const bf16x8*)vc;
  bf16x8 vb0 = *(const bf16x8*)(vc + 512);
  bf16x8 kf1 = *(const bf16x8*)(kc + 512);
  bf16x8 va1 = *(const bf16x8*)(vc + 1024);
  bf16x8 vb1 = *(const bf16x8*)(vc + 1536);

  f32x16 S0 = __builtin_amdgcn_mfma_f32_32x32x16_bf16(kf0, qf, zero, 0, 0, 0);

  for (int c = 0; c < 25; ++c) {
    int cn = (c + 2 < 25) ? c + 2 : 24;    // 2-deep prefetch (clamped)
    bf16x8 kf2 = *(const bf16x8*)(kc + (size_t)cn * 512);
    bf16x8 va2 = *(const bf16x8*)(vc + (size_t)cn * 1024);
    bf16x8 vb2 = *(const bf16x8*)(vc + (size_t)cn * 1024 + 512);

    // S for chunk c+1 from fragments loaded >=1 iteration ago (latency hidden;
    // independent of this chunk's exp/PV chain). Last iter: dummy, discarded.
    f32x16 S1 = __builtin_amdgcn_mfma_f32_32x32x16_bf16(kf1, qf, zero, 0, 0, 0);

    BF8U f0, f1;
#pragma unroll
    for (int i = 0; i < 4; ++i) {
      f0.u[i] = packbf2(__builtin_amdgcn_exp2f(S0[2 * i]),
                        __builtin_amdgcn_exp2f(S0[2 * i + 1]));
      f1.u[i] = packbf2(__builtin_amdgcn_exp2f(S0[8 + 2 * i]),
                        __builtin_amdgcn_exp2f(S0[9 + 2 * i]));
    }

    acc0 = __builtin_amdgcn_mfma_f32_32x32x16_bf16(va0, f0.v, acc0, 0, 0, 0);
    acc1 = __builtin_amdgcn_mfma_f32_32x32x16_bf16(vb0, f1.v, acc1, 0, 0, 0);

    S0 = S1;
    kf0 = kf1; va0 = va1; vb0 = vb1;
    kf1 = kf2; va1 = va2; vb1 = vb2;
  }

  f32x16 acc;
#pragma unroll
  for (int i = 0; i < 16; ++i) acc[i] = acc0[i] + acc1[i];

  // acc: col q = ln, row d = (r&3)+8*(r>>2)+4*hf. Row16 (denom) = acc[8]@hf0.
  unsigned short* prow =
      &Pb[(size_t)(half * 2 + b) * (NQ * DIM) + (size_t)(q0 + ln) * DIM + h * 16 + 4 * hf];
  uint2 w0, w1;
  w0.x = packbf2(acc[0], acc[1]); w0.y = packbf2(acc[2], acc[3]);
  w1.x = packbf2(acc[4], acc[5]); w1.y = packbf2(acc[6], acc[7]);
  *(uint2*)&prow[0] = w0;
  *(uint2*)&prow[8] = w1;
  if (!hf)
    Lsum[(size_t)(half * 2 + b) * (HEADS * NQ) + (size_t)h * NQ + q0 + ln] = acc[8];
}

// ---------------------------------------------------------------------------
// proj_comb: fused combine (2 halves) + reference scramble + proj GEMM.
// As[s_local][c] = sum(P)/sum(L) at flat att index f=c*6400+s (the
// transpose/reshape scramble). grid (200, 2), block 256.
// ---------------------------------------------------------------------------
__global__ __launch_bounds__(256) void proj_comb(
    const unsigned short* __restrict__ Pb, const float* __restrict__ Lsum,
    const bf16_t* __restrict__ Wb, const float* __restrict__ p_b,
    float* __restrict__ Out)
{
  __shared__ __align__(16) unsigned short As[32][136];
  int t = threadIdx.x;
  int b = blockIdx.y;
  int s0 = blockIdx.x * 32;

  {
    int tx = t & 31, cg = t >> 5;          // lane sweeps s (coalesced in f)
#pragma unroll
    for (int it = 0; it < 16; ++it) {
      int c = cg * 16 + it;
      int f = c * NQ + s0 + tx;            // flat att index = n*128 + h*16+d
      int n = f >> 7, hh = (f >> 4) & 7;
      float p0 = __uint_as_float((unsigned)Pb[(size_t)b * (NQ * DIM) + f] << 16);
      float p1 = __uint_as_float((unsigned)Pb[(size_t)(2 + b) * (NQ * DIM) + f] << 16);
      float L = Lsum[(size_t)b * (HEADS * NQ) + (size_t)hh * NQ + n] +
                Lsum[(size_t)(2 + b) * (HEADS * NQ) + (size_t)hh * NQ + n];
      As[tx][c] = f2bf((p0 + p1) / L);
    }
  }
  __syncthreads();

  int ln = t & 31, hf = (t >> 5) & 1, wid = t >> 6;
  int o = wid * 32 + ln;
  const bf16_t* brow = &Wb[49152 + (size_t)o * DIM + hf * 8];
  const unsigned short* arow = &As[ln][hf * 8];
  f32x16 acc = {};
#pragma unroll
  for (int c0 = 0; c0 < 128; c0 += 16) {
    bf16x8 af = *(const bf16x8*)&arow[c0];
    bf16x8 bf = *(const bf16x8*)&brow[c0];
    acc = __builtin_amdgcn_mfma_f32_32x32x16_bf16(af, bf, acc, 0, 0, 0);
  }
  float bv = p_b[o];
  float* obase = &Out[((size_t)b * DIM + o) * NQ + s0 + 4 * hf];
#pragma unroll
  for (int g = 0; g < 4; ++g) {
    float4 r;
    r.x = acc[4 * g + 0] + bv; r.y = acc[4 * g + 1] + bv;
    r.z = acc[4 * g + 2] + bv; r.w = acc[4 * g + 3] + bv;
    *(float4*)&obase[8 * g] = r;
  }
}

// ---------------------------------------------------------------------------
extern "C" void kernel_launch(void* const* d_in, const int* in_sizes, int n_in,
                              void* d_out, int out_size, void* d_ws, size_t ws_size,
                              hipStream_t stream)
{
  const float* x    = (const float*)d_in[0];
  const float* q_w  = (const float*)d_in[1];
  const float* q_b  = (const float*)d_in[2];
  const float* k_w  = (const float*)d_in[3];
  const float* k_b  = (const float*)d_in[4];
  const float* v_w  = (const float*)d_in[5];
  const float* v_b  = (const float*)d_in[6];
  const float* sr_w = (const float*)d_in[7];
  const float* sr_b = (const float*)d_in[8];
  const float* bng  = (const float*)d_in[9];
  const float* bnb  = (const float*)d_in[10];
  const float* bnm  = (const float*)d_in[11];
  const float* bnv  = (const float*)d_in[12];
  const float* p_w  = (const float*)d_in[13];
  const float* p_b  = (const float*)d_in[14];
  float* out = (float*)d_out;

  float* ws = (float*)d_ws;
  // f32-slot layout, no aliasing (~19.9 MB of the 256+ MB ws):
  bf16_t* Xb   = (bf16_t*)(ws);             // [0, 819200)
  bf16_t* X4b  = (bf16_t*)(ws + 819200);    // [819200, 1638400)
  bf16_t* Qb   = (bf16_t*)(ws + 1638400);   // [1638400, 2457600)
  bf16_t* Kp   = (bf16_t*)(ws + 2457600);   // [2457600, 2662400)
  bf16_t* Vp   = (bf16_t*)(ws + 2662400);   // [2662400, 3072000)
  float*  Lsum = ws + 3072000;              // [3072000, 3276800)
  bf16_t* Wb   = (bf16_t*)(ws + 3276800);   // [3276800, 3342336)
  bf16_t* Pb   = (bf16_t*)(ws + 3342336);   // [3342336, 4980736) 4 slices

  const float sl = 0.25f * LOG2E;  // SCALE * log2(e) folded into Q

  // 1. transpose + im2col + weight cast + Vp denom fill (fused)
  prep_all<<<dim3(8000), dim3(256), 0, stream>>>(
      x, q_w, k_w, v_w, p_w, sr_w,
      (unsigned short*)Xb, (unsigned short*)Wb,
      (unsigned short*)X4b, (unsigned short*)Vp);

  // 2. sr->k->v (blocks 0-49, LDS-fused) + q (blocks 50-249)
  mgemm_qsrkv<<<dim3(250, NBATCH), dim3(256), 0, stream>>>(
      Xb, X4b, Wb, q_b, sr_b, k_b, v_b, bng, bnb, bnm, bnv,
      (unsigned short*)Qb, (unsigned short*)Kp, (unsigned short*)Vp, sl);

  // 3. attention partials (kv-split = 2, software-pipelined)
  attn_split<<<dim3(NQ / 128, HEADS, 4), dim3(256), 0, stream>>>(
      Qb, Kp, Vp, (unsigned short*)Pb, Lsum);

  // 4. combine + scramble + proj -> f32 chan-major final output (B,128,80,80)
  proj_comb<<<dim3(200, NBATCH), dim3(256), 0, stream>>>(
      (const unsigned short*)Pb, Lsum, Wb, p_b, out);
}

// Round 13
// 154.891 us; speedup vs baseline: 1.1004x; 1.0045x over previous
//
#include <hip/hip_runtime.h>
#include <hip/hip_bf16.h>
#include <cmath>

#define DIM 128
#define HEADS 8
#define NBATCH 2
#define NQ 6400   /* 80*80 */
#define NKV 1600  /* 40*40 */
#define NC 50     /* kv chunks of 32 */
#define BN_EPS 1e-5f
#define LOG2E 1.4426950408889634f

typedef __bf16 bf16_t;
typedef __attribute__((ext_vector_type(8))) __bf16 bf16x8;
typedef __attribute__((ext_vector_type(16))) float f32x16;

union BF8U { bf16x8 v; unsigned u[4]; };

// pack two f32 -> packed bf16 (a->lo, b->hi); lowers to v_cvt_pk_bf16_f32 (RNE)
__device__ inline unsigned packbf2(float a, float b) {
  union { __hip_bfloat162 v; unsigned u; } r;
  r.v = __float22bfloat162_rn(make_float2(a, b));
  return r.u;
}

__device__ inline unsigned short f2bf(float v) {
  unsigned u = __float_as_uint(v);
  return (unsigned short)((u + 0x7FFFu + ((u >> 16) & 1u)) >> 16);
}

// ---------------------------------------------------------------------------
// prep_all: fused transpose + COALESCED im2col + weight cast + Vp denom fill.
// blocks [0,1600):    x (B,128,6400) f32 -> Xb (B,6400,128) bf16 (LDS tile)
// blocks [1600,2240): im2col, LDS-tiled & two-side coalesced. Block =
//                     (b, i, cg): reads x[c0..c0+15][rows 2i,2i+1][0..79]
//                     as contiguous 160-f32 runs; writes X4b[b][i*40+j][c4]
//                     as contiguous 64-short runs per token.
// blocks [2240,2880): e-indexed aux: weight cast (q|k|v|proj|sr -> Wb) and
//                     Vp lane-16 (softmax denominator) fill.
// ---------------------------------------------------------------------------
__global__ __launch_bounds__(256) void prep_all(
    const float* __restrict__ x,
    const float* __restrict__ qw, const float* __restrict__ kw,
    const float* __restrict__ vw, const float* __restrict__ pw,
    const float* __restrict__ srw,
    unsigned short* __restrict__ Xb,
    unsigned short* __restrict__ Wb,
    unsigned short* __restrict__ X4b,
    unsigned short* __restrict__ Vp)
{
  int t = threadIdx.x;
  int bx = blockIdx.x;
  if (bx < 1600) {                 // ---- transpose part ----
    __shared__ float tile[32][33];
    int tx = t & 31, ty = t >> 5;
    int b = bx / 800;
    int rem = bx % 800;
    int c0 = (rem / 200) * 32, s0 = (rem % 200) * 32;
#pragma unroll
    for (int r = 0; r < 32; r += 8)
      tile[ty + r][tx] = x[((size_t)b * DIM + c0 + ty + r) * NQ + s0 + tx];
    __syncthreads();
#pragma unroll
    for (int r = 0; r < 32; r += 8)
      Xb[((size_t)b * NQ + s0 + ty + r) * DIM + c0 + tx] = f2bf(tile[tx][ty + r]);
    return;
  }
  if (bx < 2240) {                 // ---- im2col part (640 blocks) ----
    __shared__ float itile[16][164];   // 164 pad: 2-way LDS alias only (free)
    int idx0 = bx - 1600;              // b(2) x i(40) x cg(8)
    int b  = idx0 / 320;
    int rem = idx0 % 320;
    int i  = rem / 8;
    int c0 = (rem % 8) * 16;
    // read: 16 c-rows x 160 f32 (rows 2i, 2i+1 concatenated), coalesced
    const float* xb = x + ((size_t)b * DIM + c0) * NQ + (size_t)i * 160;
#pragma unroll
    for (int k = 0; k < 10; ++k) {
      int idx = t + k * 256;           // 2560 total
      int r = idx / 160, col = idx % 160;
      itile[r][col] = xb[(size_t)r * NQ + col];
    }
    __syncthreads();
    // write: 40 tokens x 64 c4, coalesced 128B runs
    unsigned short* ob = X4b + ((size_t)b * NKV + (size_t)i * 40) * 512 + c0 * 4;
#pragma unroll
    for (int k = 0; k < 10; ++k) {
      int idx = t + k * 256;           // 2560 total
      int j = idx >> 6, cc = idx & 63;
      int cr = cc >> 2, ky = (cc >> 1) & 1, kx = cc & 1;
      ob[(size_t)j * 512 + cc] = f2bf(itile[cr][ky * 80 + 2 * j + kx]);
    }
    return;
  }
  // ---- aux part ----
  int e = (bx - 2240) * 256 + t;     // 163,840 range
  if (e < 131072) {                  // weight cast: q|k|v|proj 16384 ea | sr 65536
    const float* src; int idx;
    if (e < 16384)      { src = qw;  idx = e; }
    else if (e < 32768) { src = kw;  idx = e - 16384; }
    else if (e < 49152) { src = vw;  idx = e - 32768; }
    else if (e < 65536) { src = pw;  idx = e - 49152; }
    else                { src = srw; idx = e - 65536; }
    Wb[e] = f2bf(src[idx]);
  }
  if (e < NBATCH * HEADS * NC * 32) {   // Vp lane-16 (denominator) fill: 25600
    int cid = e >> 5;
    int pos = e & 31;
    size_t addr = (size_t)cid * 1024 + 256 + ((pos & 16) ? 512 : 0) + (pos & 15);
    Vp[addr] = 0x3F80;               // 1.0 bf16
  }
}

// ---------------------------------------------------------------------------
// Fused q + (sr -> k -> v) GEMM (round-11/12 verbatim). Block 256 = 4 waves.
// blocks [0,50):    sr tile (C=512) -> BN+ReLU -> LDS -> k GEMM + v GEMM with
//                   fragment-major Kp/Vp epilogues.
// blocks [50,250):  q tile of Xb (C=128) -> Qb bf16 token-major, *SCALE*log2e
// ---------------------------------------------------------------------------
__global__ __launch_bounds__(256) void mgemm_qsrkv(
    const bf16_t* __restrict__ Xb, const bf16_t* __restrict__ X4b,
    const bf16_t* __restrict__ Wb,
    const float* __restrict__ q_b, const float* __restrict__ sr_b,
    const float* __restrict__ k_b, const float* __restrict__ v_b,
    const float* __restrict__ bng, const float* __restrict__ bnb,
    const float* __restrict__ bnm, const float* __restrict__ bnv,
    unsigned short* __restrict__ Qb,
    unsigned short* __restrict__ Kp, unsigned short* __restrict__ Vp,
    float sl)
{
  __shared__ __align__(16) unsigned short xs[32][136];
  int t = threadIdx.x;
  int ln = t & 31, hf = (t >> 5) & 1, wid = t >> 6;
  int b = blockIdx.y;
  int o = wid * 32 + ln;

  if (blockIdx.x < 50) {             // ---- sr -> k -> v part ----
    int s0 = blockIdx.x * 32;
    const bf16_t* arow = &X4b[((size_t)b * NKV + s0 + ln) * 512 + hf * 8];
    const bf16_t* brow = &Wb[65536 + (size_t)o * 512 + hf * 8];
    f32x16 acc = {};
#pragma unroll 8
    for (int c0 = 0; c0 < 512; c0 += 16) {
      bf16x8 af = *(const bf16x8*)&arow[c0];
      bf16x8 bf = *(const bf16x8*)&brow[c0];
      acc = __builtin_amdgcn_mfma_f32_32x32x16_bf16(af, bf, acc, 0, 0, 0);
    }
    float bv = sr_b[o];
    float inv = bng[o] / sqrtf(bnv[o] + BN_EPS);
    float b2 = bnb[o] - bnm[o] * inv;
#pragma unroll
    for (int g = 0; g < 4; ++g)
#pragma unroll
      for (int j = 0; j < 4; ++j) {
        int s = 8 * g + 4 * hf + j;
        xs[s][o] = f2bf(fmaxf((acc[4 * g + j] + bv) * inv + b2, 0.f));
      }
    __syncthreads();

    // k + v GEMMs (C=128) off the LDS tile
    const unsigned short* ar2 = &xs[ln][hf * 8];
    const bf16_t* kbrow = &Wb[16384 + (size_t)o * DIM + hf * 8];
    const bf16_t* vbrow = &Wb[32768 + (size_t)o * DIM + hf * 8];
    f32x16 ka = {}, va = {};
#pragma unroll
    for (int c0 = 0; c0 < 128; c0 += 16) {
      bf16x8 af = *(const bf16x8*)&ar2[c0];
      bf16x8 kb = *(const bf16x8*)&kbrow[c0];
      bf16x8 vb = *(const bf16x8*)&vbrow[c0];
      ka = __builtin_amdgcn_mfma_f32_32x32x16_bf16(af, kb, ka, 0, 0, 0);
      va = __builtin_amdgcn_mfma_f32_32x32x16_bf16(af, vb, va, 0, 0, 0);
    }
    int hloc = o >> 4, d = o & 15;
    {
      float kb2 = k_b[o];
      size_t CB = (((size_t)b * HEADS + hloc) * NC + (s0 >> 5)) * 512;
#pragma unroll
      for (int g = 0; g < 4; ++g)
#pragma unroll
        for (int j = 0; j < 4; ++j) {
          int sl2 = 8 * g + 4 * hf + j;              // s_local row
          Kp[CB + sl2 * 16 + d] = f2bf(ka[4 * g + j] + kb2);
        }
    }
    {
      float vb2 = v_b[o];
      size_t CB = (((size_t)b * HEADS + hloc) * NC + (s0 >> 5)) * 1024;
      uint4 w0, w1;
      w0.x = packbf2(va[0] + vb2, va[1] + vb2);
      w0.y = packbf2(va[2] + vb2, va[3] + vb2);
      w0.z = packbf2(va[4] + vb2, va[5] + vb2);
      w0.w = packbf2(va[6] + vb2, va[7] + vb2);
      w1.x = packbf2(va[8] + vb2, va[9] + vb2);
      w1.y = packbf2(va[10] + vb2, va[11] + vb2);
      w1.z = packbf2(va[12] + vb2, va[13] + vb2);
      w1.w = packbf2(va[14] + vb2, va[15] + vb2);
      *(uint4*)&Vp[CB + d * 16 + hf * 8] = w0;       // va block
      *(uint4*)&Vp[CB + 512 + d * 16 + hf * 8] = w1; // vb block
    }
  } else {                           // ---- q part (C = 128) ----
    int s0 = (blockIdx.x - 50) * 32;
    const bf16_t* arow = &Xb[((size_t)b * NQ + s0 + ln) * DIM + hf * 8];
    const bf16_t* brow = &Wb[(size_t)o * DIM + hf * 8];
    f32x16 acc = {};
#pragma unroll
    for (int c0 = 0; c0 < 128; c0 += 16) {
      bf16x8 af = *(const bf16x8*)&arow[c0];
      bf16x8 bf = *(const bf16x8*)&brow[c0];
      acc = __builtin_amdgcn_mfma_f32_32x32x16_bf16(af, bf, acc, 0, 0, 0);
    }
    float bv = q_b[o];
#pragma unroll
    for (int g = 0; g < 4; ++g)
#pragma unroll
      for (int j = 0; j < 4; ++j) {
        int s = s0 + 8 * g + 4 * hf + j;
        Qb[((size_t)b * NQ + s) * DIM + o] = f2bf((acc[4 * g + j] + bv) * sl);
      }
  }
}

// ---------------------------------------------------------------------------
// MFMA attention (round-12 verbatim), SOFTWARE-PIPELINED: kv-split=2,
// fragment-major K/V, 2-deep fragment prefetch, S computed one chunk ahead,
// dual accumulators. grid (50, 8, 4): z = b + 2*half. block 256.
// ---------------------------------------------------------------------------
__global__ __launch_bounds__(256, 4) void attn_split(
    const bf16_t* __restrict__ Qb, const bf16_t* __restrict__ Kp,
    const bf16_t* __restrict__ Vp, unsigned short* __restrict__ Pb,
    float* __restrict__ Lsum)
{
  const int t = threadIdx.x;
  const int ln = t & 31, hf = (t >> 5) & 1, wid = t >> 6;
  const int h = blockIdx.y;
  const int b = blockIdx.z & 1, half = blockIdx.z >> 1;
  const int q0 = blockIdx.x * 128 + wid * 32;

  bf16x8 qf = *(const bf16x8*)&Qb[((size_t)b * NQ + q0 + ln) * DIM + h * 16 + hf * 8];
  const int bh = b * HEADS + h;
  const bf16_t* kc = &Kp[((size_t)bh * NC + half * 25) * 512 + ln * 16 + hf * 8];
  const bf16_t* vc = &Vp[((size_t)bh * NC + half * 25) * 1024 + ln * 16 + hf * 8];

  f32x16 acc0 = {}, acc1 = {};
  const f32x16 zero = {};

  bf16x8 kf0 = *(const bf16x8*)kc;
  bf16x8 va0 = *(const bf16x8*)vc;
  bf16x8 vb0 = *(const bf16x8*)(vc + 512);
  bf16x8 kf1 = *(const bf16x8*)(kc + 512);
  bf16x8 va1 = *(const bf16x8*)(vc + 1024);
  bf16x8 vb1 = *(const bf16x8*)(vc + 1536);

  f32x16 S0 = __builtin_amdgcn_mfma_f32_32x32x16_bf16(kf0, qf, zero, 0, 0, 0);

  for (int c = 0; c < 25; ++c) {
    int cn = (c + 2 < 25) ? c + 2 : 24;    // 2-deep prefetch (clamped)
    bf16x8 kf2 = *(const bf16x8*)(kc + (size_t)cn * 512);
    bf16x8 va2 = *(const bf16x8*)(vc + (size_t)cn * 1024);
    bf16x8 vb2 = *(const bf16x8*)(vc + (size_t)cn * 1024 + 512);

    f32x16 S1 = __builtin_amdgcn_mfma_f32_32x32x16_bf16(kf1, qf, zero, 0, 0, 0);

    BF8U f0, f1;
#pragma unroll
    for (int i = 0; i < 4; ++i) {
      f0.u[i] = packbf2(__builtin_amdgcn_exp2f(S0[2 * i]),
                        __builtin_amdgcn_exp2f(S0[2 * i + 1]));
      f1.u[i] = packbf2(__builtin_amdgcn_exp2f(S0[8 + 2 * i]),
                        __builtin_amdgcn_exp2f(S0[9 + 2 * i]));
    }

    acc0 = __builtin_amdgcn_mfma_f32_32x32x16_bf16(va0, f0.v, acc0, 0, 0, 0);
    acc1 = __builtin_amdgcn_mfma_f32_32x32x16_bf16(vb0, f1.v, acc1, 0, 0, 0);

    S0 = S1;
    kf0 = kf1; va0 = va1; vb0 = vb1;
    kf1 = kf2; va1 = va2; vb1 = vb2;
  }

  f32x16 acc;
#pragma unroll
  for (int i = 0; i < 16; ++i) acc[i] = acc0[i] + acc1[i];

  // acc: col q = ln, row d = (r&3)+8*(r>>2)+4*hf. Row16 (denom) = acc[8]@hf0.
  unsigned short* prow =
      &Pb[(size_t)(half * 2 + b) * (NQ * DIM) + (size_t)(q0 + ln) * DIM + h * 16 + 4 * hf];
  uint2 w0, w1;
  w0.x = packbf2(acc[0], acc[1]); w0.y = packbf2(acc[2], acc[3]);
  w1.x = packbf2(acc[4], acc[5]); w1.y = packbf2(acc[6], acc[7]);
  *(uint2*)&prow[0] = w0;
  *(uint2*)&prow[8] = w1;
  if (!hf)
    Lsum[(size_t)(half * 2 + b) * (HEADS * NQ) + (size_t)h * NQ + q0 + ln] = acc[8];
}

// ---------------------------------------------------------------------------
// proj_comb (round-12 verbatim): fused combine (2 halves) + reference
// scramble + proj GEMM. grid (200, 2), block 256.
// ---------------------------------------------------------------------------
__global__ __launch_bounds__(256) void proj_comb(
    const unsigned short* __restrict__ Pb, const float* __restrict__ Lsum,
    const bf16_t* __restrict__ Wb, const float* __restrict__ p_b,
    float* __restrict__ Out)
{
  __shared__ __align__(16) unsigned short As[32][136];
  int t = threadIdx.x;
  int b = blockIdx.y;
  int s0 = blockIdx.x * 32;

  {
    int tx = t & 31, cg = t >> 5;          // lane sweeps s (coalesced in f)
#pragma unroll
    for (int it = 0; it < 16; ++it) {
      int c = cg * 16 + it;
      int f = c * NQ + s0 + tx;            // flat att index = n*128 + h*16+d
      int n = f >> 7, hh = (f >> 4) & 7;
      float p0 = __uint_as_float((unsigned)Pb[(size_t)b * (NQ * DIM) + f] << 16);
      float p1 = __uint_as_float((unsigned)Pb[(size_t)(2 + b) * (NQ * DIM) + f] << 16);
      float L = Lsum[(size_t)b * (HEADS * NQ) + (size_t)hh * NQ + n] +
                Lsum[(size_t)(2 + b) * (HEADS * NQ) + (size_t)hh * NQ + n];
      As[tx][c] = f2bf((p0 + p1) / L);
    }
  }
  __syncthreads();

  int ln = t & 31, hf = (t >> 5) & 1, wid = t >> 6;
  int o = wid * 32 + ln;
  const bf16_t* brow = &Wb[49152 + (size_t)o * DIM + hf * 8];
  const unsigned short* arow = &As[ln][hf * 8];
  f32x16 acc = {};
#pragma unroll
  for (int c0 = 0; c0 < 128; c0 += 16) {
    bf16x8 af = *(const bf16x8*)&arow[c0];
    bf16x8 bf = *(const bf16x8*)&brow[c0];
    acc = __builtin_amdgcn_mfma_f32_32x32x16_bf16(af, bf, acc, 0, 0, 0);
  }
  float bv = p_b[o];
  float* obase = &Out[((size_t)b * DIM + o) * NQ + s0 + 4 * hf];
#pragma unroll
  for (int g = 0; g < 4; ++g) {
    float4 r;
    r.x = acc[4 * g + 0] + bv; r.y = acc[4 * g + 1] + bv;
    r.z = acc[4 * g + 2] + bv; r.w = acc[4 * g + 3] + bv;
    *(float4*)&obase[8 * g] = r;
  }
}

// ---------------------------------------------------------------------------
extern "C" void kernel_launch(void* const* d_in, const int* in_sizes, int n_in,
                              void* d_out, int out_size, void* d_ws, size_t ws_size,
                              hipStream_t stream)
{
  const float* x    = (const float*)d_in[0];
  const float* q_w  = (const float*)d_in[1];
  const float* q_b  = (const float*)d_in[2];
  const float* k_w  = (const float*)d_in[3];
  const float* k_b  = (const float*)d_in[4];
  const float* v_w  = (const float*)d_in[5];
  const float* v_b  = (const float*)d_in[6];
  const float* sr_w = (const float*)d_in[7];
  const float* sr_b = (const float*)d_in[8];
  const float* bng  = (const float*)d_in[9];
  const float* bnb  = (const float*)d_in[10];
  const float* bnm  = (const float*)d_in[11];
  const float* bnv  = (const float*)d_in[12];
  const float* p_w  = (const float*)d_in[13];
  const float* p_b  = (const float*)d_in[14];
  float* out = (float*)d_out;

  float* ws = (float*)d_ws;
  // f32-slot layout, no aliasing (~19.9 MB of the 256+ MB ws):
  bf16_t* Xb   = (bf16_t*)(ws);             // [0, 819200)
  bf16_t* X4b  = (bf16_t*)(ws + 819200);    // [819200, 1638400)
  bf16_t* Qb   = (bf16_t*)(ws + 1638400);   // [1638400, 2457600)
  bf16_t* Kp   = (bf16_t*)(ws + 2457600);   // [2457600, 2662400)
  bf16_t* Vp   = (bf16_t*)(ws + 2662400);   // [2662400, 3072000)
  float*  Lsum = ws + 3072000;              // [3072000, 3276800)
  bf16_t* Wb   = (bf16_t*)(ws + 3276800);   // [3276800, 3342336)
  bf16_t* Pb   = (bf16_t*)(ws + 3342336);   // [3342336, 4980736) 4 slices

  const float sl = 0.25f * LOG2E;  // SCALE * log2(e) folded into Q

  // 1. transpose + coalesced im2col + weight cast + Vp denom fill (fused)
  prep_all<<<dim3(2880), dim3(256), 0, stream>>>(
      x, q_w, k_w, v_w, p_w, sr_w,
      (unsigned short*)Xb, (unsigned short*)Wb,
      (unsigned short*)X4b, (unsigned short*)Vp);

  // 2. sr->k->v (blocks 0-49, LDS-fused) + q (blocks 50-249)
  mgemm_qsrkv<<<dim3(250, NBATCH), dim3(256), 0, stream>>>(
      Xb, X4b, Wb, q_b, sr_b, k_b, v_b, bng, bnb, bnm, bnv,
      (unsigned short*)Qb, (unsigned short*)Kp, (unsigned short*)Vp, sl);

  // 3. attention partials (kv-split = 2, software-pipelined)
  attn_split<<<dim3(NQ / 128, HEADS, 4), dim3(256), 0, stream>>>(
      Qb, Kp, Vp, (unsigned short*)Pb, Lsum);

  // 4. combine + scramble + proj -> f32 chan-major final output (B,128,80,80)
  proj_comb<<<dim3(200, NBATCH), dim3(256), 0, stream>>>(
      (const unsigned short*)Pb, Lsum, Wb, p_b, out);
}